// Round 7
// baseline (699.538 us; speedup 1.0000x reference)
//
#include <hip/hip_runtime.h>
#include <math.h>

// ---------------------------------------------------------------------------
// GAT encoder: 3 GATConv layers (H=4,4,1) + ELU + global max pool.
// GEMMs on matrix cores via bf16x3 split emulation (hi/lo bf16 per fp32;
// hi*hi+hi*lo+lo*hi with fp32 MFMA accumulate; rel err ~2^-17).
// mfma_f32_32x32x16_bf16, 128-row block, wave tile WMxWN. The epilogue also
// computes As/Ad = z . att vectors via shfl butterfly (each wave owns exactly
// one head's 64 cols), removing the separate GEMV pass.
// Aggregate: wave-per-(node,head); 4-edges-per-float4-load gather (lane =
// group x col4), predicated broadcast loads for idx/weight, 2-shfl combine.
// Layer 2 fuses the pooled atomicMax. Final: decode.
// ---------------------------------------------------------------------------

typedef __attribute__((ext_vector_type(8))) short short8v;
typedef __attribute__((ext_vector_type(16))) float f32x16;

__device__ __forceinline__ float lrelu(float x) { return x > 0.f ? x : 0.2f * x; }

__device__ __forceinline__ unsigned short f2bf(float x) {  // RNE
    unsigned u = __float_as_uint(x);
    return (unsigned short)((u + 0x7FFFu + ((u >> 16) & 1u)) >> 16);
}
__device__ __forceinline__ float bf2f(unsigned short h) {
    return __uint_as_float(((unsigned)h) << 16);
}

// ----------------------------- CSR build -----------------------------------
__global__ void k_count(const int* __restrict__ dst, int E, int* __restrict__ deg) {
    int e = blockIdx.x * 256 + threadIdx.x;
    if (e < E) atomicAdd(&deg[dst[e]], 1);
}

// rowptr/cursor include +1 slot per node for the self-loop
__global__ void k_scan(const int* __restrict__ deg, int* __restrict__ rowptr,
                       int* __restrict__ cursor, int N) {
    __shared__ int sums[1024];
    const int t = threadIdx.x;
    const int per = (N + 1023) >> 10;
    const int b0 = t * per;
    const int b1 = min(b0 + per, N);
    int s = 0;
    for (int i = b0; i < b1; i++) s += deg[i] + 1;
    sums[t] = s;
    __syncthreads();
    for (int off = 1; off < 1024; off <<= 1) {
        int v = (t >= off) ? sums[t - off] : 0;
        __syncthreads();
        sums[t] += v;
        __syncthreads();
    }
    int run = (t == 0) ? 0 : sums[t - 1];
    for (int i = b0; i < b1; i++) {
        rowptr[i] = run;
        cursor[i] = run;
        run += deg[i] + 1;
    }
    if (t == 1023) rowptr[N] = sums[1023];
}

__global__ void k_selfloop(int* __restrict__ cursor, int* __restrict__ col,
                           int* __restrict__ dstv, int N) {
    int n = blockIdx.x * 256 + threadIdx.x;
    if (n < N) {
        int p = atomicAdd(&cursor[n], 1);
        col[p] = n;
        dstv[p] = n;
    }
}

__global__ void k_scatter(const int* __restrict__ src, const int* __restrict__ dst, int E,
                          int* __restrict__ cursor, int* __restrict__ col,
                          int* __restrict__ dstv) {
    int e = blockIdx.x * 256 + threadIdx.x;
    if (e < E) {
        int d = dst[e];
        int p = atomicAdd(&cursor[d], 1);
        col[p] = src[e];
        dstv[p] = d;
    }
}

// ----------------------------- converts --------------------------------------
__global__ void k_conv(const float* __restrict__ in, unsigned short* __restrict__ hi,
                       unsigned short* __restrict__ lo, int M) {
    int i = blockIdx.x * 256 + threadIdx.x;
    if (i < M) {
        float x = in[i];
        unsigned short h = f2bf(x);
        hi[i] = h;
        lo[i] = f2bf(x - bf2f(h));
    }
}

// W[k][C] -> Wt hi/lo [C][K]
template <int K, int C>
__global__ void k_wconv(const float* __restrict__ W, unsigned short* __restrict__ thi,
                        unsigned short* __restrict__ tlo) {
    int i = blockIdx.x * 256 + threadIdx.x;
    if (i < K * C) {
        int c = i / K, k = i % K;
        float x = W[(size_t)k * C + c];
        unsigned short h = f2bf(x);
        thi[i] = h;
        tlo[i] = f2bf(x - bf2f(h));
    }
}

// ----------------------------- MFMA GEMM (bf16x3) ----------------------------
// Z[N,COLS] = X @ W. A = hi/lo bf16 planes [N][K]; B = Wt hi/lo [COLS][K].
// 4 waves. WAVES_N = BN/WN (wave cols), WAVES_M = 4/WAVES_N, WM = BM/WAVES_M.
// WN=64 always -> each wave owns exactly one head's columns, so the epilogue
// computes As/Ad = z . att via a 32-lane shfl butterfly (no separate GEMV).
template <int K, int COLS, int BM, int BN, int WN>
__global__ __launch_bounds__(256) void k_gemm_mx(
    const unsigned short* __restrict__ Ahi, const unsigned short* __restrict__ Alo,
    const unsigned short* __restrict__ Bhi, const unsigned short* __restrict__ Blo,
    const float* __restrict__ att_src, const float* __restrict__ att_dst,
    float* __restrict__ Z, float* __restrict__ As, float* __restrict__ Ad, int N) {
    constexpr int LD = 40;
    constexpr int WAVES_N = BN / WN;
    constexpr int WAVES_M = 4 / WAVES_N;
    constexpr int WM = BM / WAVES_M;
    constexpr int MW = WM / 32, NW = WN / 32;
    constexpr int H = COLS / 64;
    __shared__ unsigned short sa[2][BM * LD];
    __shared__ unsigned short sb[2][BN * LD];

    const int tid = threadIdx.x;
    const int n0 = blockIdx.x * BM;
    const int c0 = blockIdx.y * BN;
    const int wid = tid >> 6, lane = tid & 63;
    const int wr = wid / WAVES_N, wc = wid % WAVES_N;

    f32x16 acc[MW][NW];
#pragma unroll
    for (int m = 0; m < MW; m++)
#pragma unroll
        for (int n = 0; n < NW; n++)
#pragma unroll
            for (int i = 0; i < 16; i++) acc[m][n][i] = 0.f;

    const int srow = tid >> 2, schk = tid & 3;  // staging row / 8-ushort chunk

    for (int kb = 0; kb < K; kb += 32) {
        __syncthreads();
#pragma unroll
        for (int rr = 0; rr < BM / 64; rr++) {
            const int r = srow + rr * 64;
            const int row = n0 + r;
            short8v vh = {0, 0, 0, 0, 0, 0, 0, 0}, vl = {0, 0, 0, 0, 0, 0, 0, 0};
            if (row < N) {
                vh = *reinterpret_cast<const short8v*>(Ahi + (size_t)row * K + kb + schk * 8);
                vl = *reinterpret_cast<const short8v*>(Alo + (size_t)row * K + kb + schk * 8);
            }
            *reinterpret_cast<short8v*>(&sa[0][r * LD + schk * 8]) = vh;
            *reinterpret_cast<short8v*>(&sa[1][r * LD + schk * 8]) = vl;
        }
#pragma unroll
        for (int rr = 0; rr < BN / 64; rr++) {
            const int cc = srow + rr * 64;
            const short8v vh =
                *reinterpret_cast<const short8v*>(Bhi + (size_t)(c0 + cc) * K + kb + schk * 8);
            const short8v vl =
                *reinterpret_cast<const short8v*>(Blo + (size_t)(c0 + cc) * K + kb + schk * 8);
            *reinterpret_cast<short8v*>(&sb[0][cc * LD + schk * 8]) = vh;
            *reinterpret_cast<short8v*>(&sb[1][cc * LD + schk * 8]) = vl;
        }
        __syncthreads();
#pragma unroll
        for (int ks = 0; ks < 2; ks++) {
            const int koff = ks * 16 + (lane >> 5) * 8;
            short8v ah[MW], al[MW], bh[NW], bl[NW];
#pragma unroll
            for (int m = 0; m < MW; m++) {
                const int ar = wr * WM + m * 32 + (lane & 31);
                ah[m] = *reinterpret_cast<const short8v*>(&sa[0][ar * LD + koff]);
                al[m] = *reinterpret_cast<const short8v*>(&sa[1][ar * LD + koff]);
            }
#pragma unroll
            for (int n = 0; n < NW; n++) {
                const int br = wc * WN + n * 32 + (lane & 31);
                bh[n] = *reinterpret_cast<const short8v*>(&sb[0][br * LD + koff]);
                bl[n] = *reinterpret_cast<const short8v*>(&sb[1][br * LD + koff]);
            }
#pragma unroll
            for (int m = 0; m < MW; m++)
#pragma unroll
                for (int n = 0; n < NW; n++) {
                    acc[m][n] = __builtin_amdgcn_mfma_f32_32x32x16_bf16(ah[m], bh[n], acc[m][n], 0, 0, 0);
                    acc[m][n] = __builtin_amdgcn_mfma_f32_32x32x16_bf16(ah[m], bl[n], acc[m][n], 0, 0, 0);
                    acc[m][n] = __builtin_amdgcn_mfma_f32_32x32x16_bf16(al[m], bh[n], acc[m][n], 0, 0, 0);
                }
        }
    }

    // C/D layout: col = lane&31 (+n*32), row = (reg&3)+8*(reg>>2)+4*(lane>>5) (+m*32)
    const int colb = c0 + wc * WN + (lane & 31);
    const int rowb = n0 + wr * WM + 4 * (lane >> 5);
#pragma unroll
    for (int m = 0; m < MW; m++)
#pragma unroll
        for (int n = 0; n < NW; n++)
#pragma unroll
            for (int r = 0; r < 16; r++) {
                const int row = rowb + m * 32 + (r & 3) + 8 * (r >> 2);
                if (row < N) Z[(size_t)row * COLS + colb + n * 32] = acc[m][n][r];
            }

    // fused As/Ad: wave's 64 cols = one head (WN=64)
    const int hh = (c0 + wc * WN) >> 6;
    float asv[NW], adv[NW];
#pragma unroll
    for (int n = 0; n < NW; n++) {
        asv[n] = att_src[colb + n * 32];
        adv[n] = att_dst[colb + n * 32];
    }
#pragma unroll
    for (int m = 0; m < MW; m++)
#pragma unroll
        for (int r = 0; r < 16; r++) {
            const int row = rowb + m * 32 + (r & 3) + 8 * (r >> 2);
            float ps = 0.f, pd = 0.f;
#pragma unroll
            for (int n = 0; n < NW; n++) {
                ps = fmaf(acc[m][n][r], asv[n], ps);
                pd = fmaf(acc[m][n][r], adv[n], pd);
            }
#pragma unroll
            for (int off = 1; off < 32; off <<= 1) {
                ps += __shfl_xor(ps, off, 64);
                pd += __shfl_xor(pd, off, 64);
            }
            if ((lane & 31) == 0 && row < N) {
                As[(size_t)row * H + hh] = ps;
                Ad[(size_t)row * H + hh] = pd;
            }
        }
}

// ----------------------------- edge weights ---------------------------------
template <int H>
__global__ void k_weights(const float* __restrict__ As, const float* __restrict__ Ad,
                          const int* __restrict__ col, const int* __restrict__ dstv,
                          float* __restrict__ wgt, int Et) {
    int p = blockIdx.x * 256 + threadIdx.x;
    if (p >= Et) return;
    const int s = col[p];
    const int n = dstv[p];
    if constexpr (H == 4) {
        const float4 a = *reinterpret_cast<const float4*>(As + (size_t)s * 4);
        const float4 d = *reinterpret_cast<const float4*>(Ad + (size_t)n * 4);
        wgt[p]                  = __expf(lrelu(a.x + d.x));
        wgt[(size_t)Et + p]     = __expf(lrelu(a.y + d.y));
        wgt[2 * (size_t)Et + p] = __expf(lrelu(a.z + d.z));
        wgt[3 * (size_t)Et + p] = __expf(lrelu(a.w + d.w));
    } else {
        wgt[p] = __expf(lrelu(As[s] + Ad[n]));
    }
}

// ----------------------------- global max pool helpers -----------------------
__device__ __forceinline__ unsigned fenc(float f) {
    unsigned u = __float_as_uint(f);
    return (u & 0x80000000u) ? ~u : (u | 0x80000000u);
}

// ----------------------------- aggregate -------------------------------------
// Wave per (node, head). Lane = (edge-group g = lane>>4, col4 cl = lane&15):
// one float4 load covers 4 edges' 256B row slices; 8 edges in flight per iter.
// Edge idx/weight via predicated 16-lane-broadcast loads (L1). Combine across
// groups with 2 shfl_xor. OUTMODE 0: bf16 hi/lo planes; 1: pooled atomicMax.
template <int H, bool DO_ELU, int OUTMODE>
__global__ __launch_bounds__(256) void k_aggregate(
    const float* __restrict__ Z, const float* __restrict__ wgt,
    const int* __restrict__ rowptr, const int* __restrict__ col,
    const float* __restrict__ bias, unsigned short* __restrict__ ohi,
    unsigned short* __restrict__ olo, const int* __restrict__ batch,
    unsigned* __restrict__ enc, int N, int Et) {
    constexpr int COLS = H * 64;
    const int tid = threadIdx.x;
    const int wv = tid >> 6;
    const int lane = tid & 63;

    int n, h;
    if constexpr (H == 4) {
        n = blockIdx.x;
        h = wv;
    } else {
        n = blockIdx.x * 4 + wv;
        h = 0;
        if (n >= N) return;
    }

    const int start = rowptr[n];
    const int total = rowptr[n + 1] - start;  // includes self-loop
    const int* __restrict__ cp = col + start;
    const float* __restrict__ wp = wgt + (size_t)h * Et + start;

    const int g = lane >> 4;
    const int cl = lane & 15;
    const float* __restrict__ Zh = Z + h * 64 + cl * 4;

    float ax = 0.f, ay = 0.f, az = 0.f, aw = 0.f, denom = 0.f;

    for (int jj = 0; jj < total; jj += 8) {
        const int e0 = jj + g;
        const int e1 = e0 + 4;
        int s0 = 0, s1 = 0;
        float w0 = 0.f, w1 = 0.f;
        if (e0 < total) {
            s0 = cp[e0];
            w0 = wp[e0];
        }
        if (e1 < total) {
            s1 = cp[e1];
            w1 = wp[e1];
        }
        const float4 z0 = *reinterpret_cast<const float4*>(Zh + (size_t)s0 * COLS);
        const float4 z1 = *reinterpret_cast<const float4*>(Zh + (size_t)s1 * COLS);
        ax = fmaf(w0, z0.x, ax);
        ay = fmaf(w0, z0.y, ay);
        az = fmaf(w0, z0.z, az);
        aw = fmaf(w0, z0.w, aw);
        ax = fmaf(w1, z1.x, ax);
        ay = fmaf(w1, z1.y, ay);
        az = fmaf(w1, z1.z, az);
        aw = fmaf(w1, z1.w, aw);
        denom += w0 + w1;
    }

    // combine the 4 edge-groups (lanes with same cl)
    ax += __shfl_xor(ax, 16, 64);
    ay += __shfl_xor(ay, 16, 64);
    az += __shfl_xor(az, 16, 64);
    aw += __shfl_xor(aw, 16, 64);
    denom += __shfl_xor(denom, 16, 64);
    ax += __shfl_xor(ax, 32, 64);
    ay += __shfl_xor(ay, 32, 64);
    az += __shfl_xor(az, 32, 64);
    aw += __shfl_xor(aw, 32, 64);
    denom += __shfl_xor(denom, 32, 64);

    if (lane < 16) {
        const float inv = 1.f / (denom + 1e-16f);
        float o[4] = {ax, ay, az, aw};
        ushort4 vh, vl;
#pragma unroll
        for (int j = 0; j < 4; j++) {
            float ov = o[j] * inv + bias[h * 64 + cl * 4 + j];
            if (DO_ELU) ov = (ov > 0.f) ? ov : expm1f(ov);
            o[j] = ov;
        }
        if constexpr (OUTMODE == 1) {
            const int gr = batch[n];
#pragma unroll
            for (int j = 0; j < 4; j++) atomicMax(&enc[gr * 64 + cl * 4 + j], fenc(o[j]));
        } else {
            unsigned short b0 = f2bf(o[0]), b1 = f2bf(o[1]), b2 = f2bf(o[2]), b3 = f2bf(o[3]);
            vh = make_ushort4(b0, b1, b2, b3);
            vl = make_ushort4(f2bf(o[0] - bf2f(b0)), f2bf(o[1] - bf2f(b1)),
                              f2bf(o[2] - bf2f(b2)), f2bf(o[3] - bf2f(b3)));
            *reinterpret_cast<ushort4*>(ohi + (size_t)n * COLS + h * 64 + cl * 4) = vh;
            *reinterpret_cast<ushort4*>(olo + (size_t)n * COLS + h * 64 + cl * 4) = vl;
        }
    }
}

__global__ void k_decode(const unsigned* __restrict__ enc, float* __restrict__ out, int M) {
    int id = blockIdx.x * 256 + threadIdx.x;
    if (id < M) {
        unsigned e = enc[id];
        unsigned u = (e & 0x80000000u) ? (e & 0x7FFFFFFFu) : ~e;
        out[id] = __uint_as_float(u);
    }
}

// ----------------------------- launch ---------------------------------------
extern "C" void kernel_launch(void* const* d_in, const int* in_sizes, int n_in,
                              void* d_out, int out_size, void* d_ws, size_t ws_size,
                              hipStream_t stream) {
    const float* x = (const float*)d_in[0];
    const int* edge_index = (const int*)d_in[1];
    const int* batch = (const int*)d_in[2];
    const float* W0 = (const float*)d_in[3];
    const float* as0 = (const float*)d_in[4];
    const float* ad0 = (const float*)d_in[5];
    const float* b0 = (const float*)d_in[6];
    const float* W1 = (const float*)d_in[7];
    const float* as1 = (const float*)d_in[8];
    const float* ad1 = (const float*)d_in[9];
    const float* b1 = (const float*)d_in[10];
    const float* W2 = (const float*)d_in[11];
    const float* as2 = (const float*)d_in[12];
    const float* ad2 = (const float*)d_in[13];
    const float* b2 = (const float*)d_in[14];

    const int N = in_sizes[0] / 64;  // nodes
    const int E = in_sizes[1] / 2;   // edges (no self-loops)
    const int G = out_size / 64;     // graphs
    const int Et = E + N;            // edges incl. self-loops

    const int* srcs = edge_index;
    const int* dsts = edge_index + E;

    char* p = (char*)d_ws;
    auto alloc = [&](size_t bytes) {
        void* r = (void*)p;
        p += (bytes + 255) & ~(size_t)255;
        return r;
    };
    float* Z = (float*)alloc((size_t)N * 256 * 4);
    unsigned short* Hbhi = (unsigned short*)alloc((size_t)N * 256 * 2);  // pre-L0: xhi
    unsigned short* Hblo = (unsigned short*)alloc((size_t)N * 256 * 2);  // pre-L0: xlo
    float* As = (float*)alloc((size_t)N * 4 * 4);
    float* Ad = (float*)alloc((size_t)N * 4 * 4);
    int* deg = (int*)alloc((size_t)N * 4);
    int* rowptr = (int*)alloc((size_t)(N + 1) * 4);
    int* cursor = (int*)alloc((size_t)N * 4);
    int* col = (int*)alloc((size_t)Et * 4);
    int* dstv = (int*)alloc((size_t)Et * 4);
    float* wgt = (float*)alloc((size_t)Et * 4 * 4);
    unsigned short* wt0h = (unsigned short*)alloc(256 * 64 * 2);
    unsigned short* wt0l = (unsigned short*)alloc(256 * 64 * 2);
    unsigned short* wt1h = (unsigned short*)alloc(256 * 256 * 2);
    unsigned short* wt1l = (unsigned short*)alloc(256 * 256 * 2);
    unsigned short* wt2h = (unsigned short*)alloc(64 * 256 * 2);
    unsigned short* wt2l = (unsigned short*)alloc(64 * 256 * 2);
    unsigned* enc = (unsigned*)alloc((size_t)G * 64 * 4);

    hipMemsetAsync(deg, 0, (size_t)N * 4, stream);
    hipMemsetAsync(enc, 0, (size_t)G * 64 * 4, stream);

    const int eb = (E + 255) / 256;
    const int nb = (N + 255) / 256;
    const int tb = (Et + 255) / 256;
    k_count<<<eb, 256, 0, stream>>>(dsts, E, deg);
    k_scan<<<1, 1024, 0, stream>>>(deg, rowptr, cursor, N);
    k_selfloop<<<nb, 256, 0, stream>>>(cursor, col, dstv, N);
    k_scatter<<<eb, 256, 0, stream>>>(srcs, dsts, E, cursor, col, dstv);

    // one-time converts
    k_conv<<<(N * 64 + 255) / 256, 256, 0, stream>>>(x, Hbhi, Hblo, N * 64);
    k_wconv<64, 256><<<(64 * 256 + 255) / 256, 256, 0, stream>>>(W0, wt0h, wt0l);
    k_wconv<256, 256><<<(256 * 256 + 255) / 256, 256, 0, stream>>>(W1, wt1h, wt1l);
    k_wconv<256, 64><<<(256 * 64 + 255) / 256, 256, 0, stream>>>(W2, wt2h, wt2l);

    const int ab = (N + 3) / 4;
    const int gm = (N + 127) / 128;

    // Layer 0: K=64 -> 256 cols, H=4, ELU
    k_gemm_mx<64, 256, 128, 128, 64><<<dim3(gm, 2), 256, 0, stream>>>(
        Hbhi, Hblo, wt0h, wt0l, as0, ad0, Z, As, Ad, N);
    k_weights<4><<<tb, 256, 0, stream>>>(As, Ad, col, dstv, wgt, Et);
    k_aggregate<4, true, 0><<<N, 256, 0, stream>>>(Z, wgt, rowptr, col, b0, Hbhi, Hblo,
                                                   nullptr, nullptr, N, Et);
    // Layer 1: K=256 -> 256 cols, H=4, ELU
    k_gemm_mx<256, 256, 128, 128, 64><<<dim3(gm, 2), 256, 0, stream>>>(
        Hbhi, Hblo, wt1h, wt1l, as1, ad1, Z, As, Ad, N);
    k_weights<4><<<tb, 256, 0, stream>>>(As, Ad, col, dstv, wgt, Et);
    k_aggregate<4, true, 0><<<N, 256, 0, stream>>>(Z, wgt, rowptr, col, b1, Hbhi, Hblo,
                                                   nullptr, nullptr, N, Et);
    // Layer 2: K=256 -> 64 cols, H=1, no ELU, fused pool
    k_gemm_mx<256, 64, 128, 64, 64><<<dim3(gm, 1), 256, 0, stream>>>(
        Hbhi, Hblo, wt2h, wt2l, as2, ad2, Z, As, Ad, N);
    k_weights<1><<<tb, 256, 0, stream>>>(As, Ad, col, dstv, wgt, Et);
    k_aggregate<1, false, 1><<<ab, 256, 0, stream>>>(Z, wgt, rowptr, col, b2, nullptr, nullptr,
                                                     batch, enc, N, Et);
    // Decode pooled maxima
    k_decode<<<(G * 64 + 255) / 256, 256, 0, stream>>>(enc, (float*)d_out, G * 64);
}

// Round 8
// 572.726 us; speedup vs baseline: 1.2214x; 1.2214x over previous
//
#include <hip/hip_runtime.h>
#include <math.h>

// ---------------------------------------------------------------------------
// GAT encoder: 3 GATConv layers (H=4,4,1) + ELU + global max pool.
// Layer 0 uses aggregate-then-project: agg_x[n,h,:] = softmax-weighted sum of
// x[src] rows (256B/edge serves all 4 heads; 4x less gather traffic than
// gathering z), then a fused post-GEMM (aggx @ W0 + b0, ELU) on matrix cores.
// Layers 1/2 keep project-then-aggregate: bf16x3 MFMA GEMM (fused As/Ad
// epilogue) + wave-per-(node,head) readlane-gather aggregate with INLINE
// softmax weights (no wgt buffer). Layer 2 fuses the pooled atomicMax.
// bf16x3: fp32 ~ hi + lo bf16; hi*hi + hi*lo + lo*hi MFMA, rel err ~2^-17.
// ---------------------------------------------------------------------------

typedef __attribute__((ext_vector_type(8))) short short8v;
typedef __attribute__((ext_vector_type(16))) float f32x16;

__device__ __forceinline__ float lrelu(float x) { return x > 0.f ? x : 0.2f * x; }

__device__ __forceinline__ unsigned short f2bf(float x) {  // RNE
    unsigned u = __float_as_uint(x);
    return (unsigned short)((u + 0x7FFFu + ((u >> 16) & 1u)) >> 16);
}
__device__ __forceinline__ float bf2f(unsigned short h) {
    return __uint_as_float(((unsigned)h) << 16);
}
__device__ __forceinline__ float readlane_f(float v, int l) {
    return __uint_as_float((unsigned)__builtin_amdgcn_readlane((int)__float_as_uint(v), l));
}

// ----------------------------- CSR build -----------------------------------
__global__ void k_count(const int* __restrict__ dst, int E, int* __restrict__ deg) {
    int e = blockIdx.x * 256 + threadIdx.x;
    if (e < E) atomicAdd(&deg[dst[e]], 1);
}

// rowptr/cursor include +1 slot per node for the self-loop
__global__ void k_scan(const int* __restrict__ deg, int* __restrict__ rowptr,
                       int* __restrict__ cursor, int N) {
    __shared__ int sums[1024];
    const int t = threadIdx.x;
    const int per = (N + 1023) >> 10;
    const int b0 = t * per;
    const int b1 = min(b0 + per, N);
    int s = 0;
    for (int i = b0; i < b1; i++) s += deg[i] + 1;
    sums[t] = s;
    __syncthreads();
    for (int off = 1; off < 1024; off <<= 1) {
        int v = (t >= off) ? sums[t - off] : 0;
        __syncthreads();
        sums[t] += v;
        __syncthreads();
    }
    int run = (t == 0) ? 0 : sums[t - 1];
    for (int i = b0; i < b1; i++) {
        rowptr[i] = run;
        cursor[i] = run;
        run += deg[i] + 1;
    }
    if (t == 1023) rowptr[N] = sums[1023];
}

// edges AND self-loops in one pass
__global__ void k_scatter(const int* __restrict__ src, const int* __restrict__ dst, int E,
                          int N, int* __restrict__ cursor, int* __restrict__ col) {
    int e = blockIdx.x * 256 + threadIdx.x;
    if (e < E) {
        int d = dst[e];
        int p = atomicAdd(&cursor[d], 1);
        col[p] = src[e];
    } else if (e < E + N) {
        int n = e - E;
        int p = atomicAdd(&cursor[n], 1);
        col[p] = n;
    }
}

// ----------------------------- weight converts -------------------------------
// W[k][C] -> Wt hi/lo [C][K]
template <int K, int C>
__global__ void k_wconv(const float* __restrict__ W, unsigned short* __restrict__ thi,
                        unsigned short* __restrict__ tlo) {
    int i = blockIdx.x * 256 + threadIdx.x;
    if (i < K * C) {
        int c = i / K, k = i % K;
        float x = W[(size_t)k * C + c];
        unsigned short h = f2bf(x);
        thi[i] = h;
        tlo[i] = f2bf(x - bf2f(h));
    }
}

// vs[h][k] = sum_c W0[k][h*64+c]*att_src[h][c]; vd likewise (layer 0 only)
__global__ void k_attvec(const float* __restrict__ W, const float* __restrict__ as,
                         const float* __restrict__ ad, float* __restrict__ vs,
                         float* __restrict__ vd) {
    int k = threadIdx.x;
    if (k >= 64) return;
    for (int h = 0; h < 4; h++) {
        float s = 0.f, d = 0.f;
        for (int c = 0; c < 64; c++) {
            float w = W[(size_t)k * 256 + h * 64 + c];
            s = fmaf(w, as[h * 64 + c], s);
            d = fmaf(w, ad[h * 64 + c], d);
        }
        vs[h * 64 + k] = s;
        vd[h * 64 + k] = d;
    }
}

// As0[n,h] = x[n,:] . vs0[h,:]  (wave per node)
__global__ __launch_bounds__(256) void k_att0(
    const float* __restrict__ X, const float* __restrict__ vs, const float* __restrict__ vd,
    float* __restrict__ As, float* __restrict__ Ad, int N) {
    const int n = blockIdx.x * 4 + (threadIdx.x >> 6);
    const int lane = threadIdx.x & 63;
    if (n >= N) return;
    const float xv = X[(size_t)n * 64 + lane];
#pragma unroll
    for (int h = 0; h < 4; h++) {
        float ps = xv * vs[h * 64 + lane];
        float pd = xv * vd[h * 64 + lane];
#pragma unroll
        for (int off = 1; off < 64; off <<= 1) {
            ps += __shfl_xor(ps, off, 64);
            pd += __shfl_xor(pd, off, 64);
        }
        if (lane == 0) {
            As[(size_t)n * 4 + h] = ps;
            Ad[(size_t)n * 4 + h] = pd;
        }
    }
}

// ----------------------------- layer-0 x-aggregate ---------------------------
// Wave per node, lane = x-dim. One 256B x-row gather per edge serves all 4
// heads (4 FMAs/float). Inline softmax weights from As/Ad. Output: normalized
// agg_x as bf16 hi/lo planes [N][4*64] (head-major), feeding the post-GEMM.
__global__ __launch_bounds__(256) void k_aggx(
    const float* __restrict__ X, const float* __restrict__ As, const float* __restrict__ Ad,
    const int* __restrict__ rowptr, const int* __restrict__ col,
    unsigned short* __restrict__ ohi, unsigned short* __restrict__ olo, int N) {
    const int n = blockIdx.x * 4 + (threadIdx.x >> 6);
    const int lane = threadIdx.x & 63;
    if (n >= N) return;

    const int start = rowptr[n];
    const int total = rowptr[n + 1] - start;  // includes self-loop
    const int* __restrict__ cp = col + start;
    const float4 adn = *reinterpret_cast<const float4*>(Ad + (size_t)n * 4);

    float a0 = 0.f, a1 = 0.f, a2 = 0.f, a3 = 0.f;
    float4 den = make_float4(0.f, 0.f, 0.f, 0.f);

    for (int base = 0; base < total; base += 64) {
        const int cnt = min(64, total - base);
        const int i = base + lane;
        int s = 0;
        float4 w = make_float4(0.f, 0.f, 0.f, 0.f);
        if (i < total) {
            s = cp[i];
            const float4 av = *reinterpret_cast<const float4*>(As + (size_t)s * 4);
            w.x = __expf(lrelu(av.x + adn.x));
            w.y = __expf(lrelu(av.y + adn.y));
            w.z = __expf(lrelu(av.z + adn.z));
            w.w = __expf(lrelu(av.w + adn.w));
        }
        den.x += w.x; den.y += w.y; den.z += w.z; den.w += w.w;

        int jj = 0;
        for (; jj + 4 <= cnt; jj += 4) {
            int sb[4];
            float w0[4], w1[4], w2[4], w3[4], xv[4];
#pragma unroll
            for (int u = 0; u < 4; u++) {
                sb[u] = __builtin_amdgcn_readlane(s, jj + u);
                w0[u] = readlane_f(w.x, jj + u);
                w1[u] = readlane_f(w.y, jj + u);
                w2[u] = readlane_f(w.z, jj + u);
                w3[u] = readlane_f(w.w, jj + u);
            }
#pragma unroll
            for (int u = 0; u < 4; u++) xv[u] = X[(size_t)sb[u] * 64 + lane];
#pragma unroll
            for (int u = 0; u < 4; u++) {
                a0 = fmaf(w0[u], xv[u], a0);
                a1 = fmaf(w1[u], xv[u], a1);
                a2 = fmaf(w2[u], xv[u], a2);
                a3 = fmaf(w3[u], xv[u], a3);
            }
        }
        for (; jj < cnt; jj++) {
            const int s0 = __builtin_amdgcn_readlane(s, jj);
            const float xv = X[(size_t)s0 * 64 + lane];
            a0 = fmaf(readlane_f(w.x, jj), xv, a0);
            a1 = fmaf(readlane_f(w.y, jj), xv, a1);
            a2 = fmaf(readlane_f(w.z, jj), xv, a2);
            a3 = fmaf(readlane_f(w.w, jj), xv, a3);
        }
    }

#pragma unroll
    for (int off = 1; off < 64; off <<= 1) {
        den.x += __shfl_xor(den.x, off, 64);
        den.y += __shfl_xor(den.y, off, 64);
        den.z += __shfl_xor(den.z, off, 64);
        den.w += __shfl_xor(den.w, off, 64);
    }
    const float o[4] = {a0 / (den.x + 1e-16f), a1 / (den.y + 1e-16f),
                        a2 / (den.z + 1e-16f), a3 / (den.w + 1e-16f)};
#pragma unroll
    for (int h = 0; h < 4; h++) {
        const unsigned short hb = f2bf(o[h]);
        ohi[(size_t)n * 256 + h * 64 + lane] = hb;
        olo[(size_t)n * 256 + h * 64 + lane] = f2bf(o[h] - bf2f(hb));
    }
}

// ----------------------------- post-GEMM (layer 0) ---------------------------
// Hb[n, h*64+c] = ELU(aggx[n, h*64+:64] @ W0[:, h*64+c] + b0[h*64+c]).
// blockIdx.y = head. A = aggx hi/lo (LDA=256, 64-col slice), B = wt0 [C][K=64].
// Output: bf16 hi/lo planes for layer 1.
__global__ __launch_bounds__(256) void k_gemm_pe(
    const unsigned short* __restrict__ Ahi, const unsigned short* __restrict__ Alo,
    const unsigned short* __restrict__ Bhi, const unsigned short* __restrict__ Blo,
    const float* __restrict__ bias, unsigned short* __restrict__ Ohi,
    unsigned short* __restrict__ Olo, int N) {
    constexpr int LD = 40, BM = 128, K = 64;
    __shared__ unsigned short sa[2][BM * LD];
    __shared__ unsigned short sb[2][64 * LD];

    const int tid = threadIdx.x;
    const int n0 = blockIdx.x * BM;
    const int hh = blockIdx.y;
    const int wid = tid >> 6, lane = tid & 63;

    const unsigned short* __restrict__ Ah = Ahi + hh * 64;
    const unsigned short* __restrict__ Al = Alo + hh * 64;
    const unsigned short* __restrict__ Bh = Bhi + hh * 64 * K;
    const unsigned short* __restrict__ Bl = Blo + hh * 64 * K;

    f32x16 acc[2];
#pragma unroll
    for (int n = 0; n < 2; n++)
#pragma unroll
        for (int i = 0; i < 16; i++) acc[n][i] = 0.f;

    const int srow = tid >> 2, schk = tid & 3;

    for (int kb = 0; kb < K; kb += 32) {
        __syncthreads();
#pragma unroll
        for (int rr = 0; rr < 2; rr++) {
            const int r = srow + rr * 64;
            const int row = n0 + r;
            short8v vh = {0, 0, 0, 0, 0, 0, 0, 0}, vl = {0, 0, 0, 0, 0, 0, 0, 0};
            if (row < N) {
                vh = *reinterpret_cast<const short8v*>(Ah + (size_t)row * 256 + kb + schk * 8);
                vl = *reinterpret_cast<const short8v*>(Al + (size_t)row * 256 + kb + schk * 8);
            }
            *reinterpret_cast<short8v*>(&sa[0][r * LD + schk * 8]) = vh;
            *reinterpret_cast<short8v*>(&sa[1][r * LD + schk * 8]) = vl;
        }
        {
            const short8v vh =
                *reinterpret_cast<const short8v*>(Bh + (size_t)srow * K + kb + schk * 8);
            const short8v vl =
                *reinterpret_cast<const short8v*>(Bl + (size_t)srow * K + kb + schk * 8);
            *reinterpret_cast<short8v*>(&sb[0][srow * LD + schk * 8]) = vh;
            *reinterpret_cast<short8v*>(&sb[1][srow * LD + schk * 8]) = vl;
        }
        __syncthreads();
#pragma unroll
        for (int ks = 0; ks < 2; ks++) {
            const int koff = ks * 16 + (lane >> 5) * 8;
            const int ar = wid * 32 + (lane & 31);
            const short8v ah = *reinterpret_cast<const short8v*>(&sa[0][ar * LD + koff]);
            const short8v al = *reinterpret_cast<const short8v*>(&sa[1][ar * LD + koff]);
            short8v bh[2], bl[2];
#pragma unroll
            for (int n = 0; n < 2; n++) {
                const int br = n * 32 + (lane & 31);
                bh[n] = *reinterpret_cast<const short8v*>(&sb[0][br * LD + koff]);
                bl[n] = *reinterpret_cast<const short8v*>(&sb[1][br * LD + koff]);
            }
#pragma unroll
            for (int n = 0; n < 2; n++) {
                acc[n] = __builtin_amdgcn_mfma_f32_32x32x16_bf16(ah, bh[n], acc[n], 0, 0, 0);
                acc[n] = __builtin_amdgcn_mfma_f32_32x32x16_bf16(ah, bl[n], acc[n], 0, 0, 0);
                acc[n] = __builtin_amdgcn_mfma_f32_32x32x16_bf16(al, bh[n], acc[n], 0, 0, 0);
            }
        }
    }

    const int rowb = n0 + wid * 32 + 4 * (lane >> 5);
#pragma unroll
    for (int n = 0; n < 2; n++) {
        const int c = (lane & 31) + n * 32;
        const float bv = bias[hh * 64 + c];
#pragma unroll
        for (int r = 0; r < 16; r++) {
            const int row = rowb + (r & 3) + 8 * (r >> 2);
            if (row < N) {
                float ov = acc[n][r] + bv;
                ov = (ov > 0.f) ? ov : expm1f(ov);
                const unsigned short hb = f2bf(ov);
                Ohi[(size_t)row * 256 + hh * 64 + c] = hb;
                Olo[(size_t)row * 256 + hh * 64 + c] = f2bf(ov - bf2f(hb));
            }
        }
    }
}

// ----------------------------- z GEMM (layers 1,2) ---------------------------
// Z[N,COLS] = X @ W (bf16x3). Epilogue also emits As/Ad = z . att (WN=64:
// each wave owns one head's 64 cols; 32-lane shfl butterfly).
template <int K, int COLS, int BM, int BN, int WN>
__global__ __launch_bounds__(256) void k_gemm_z(
    const unsigned short* __restrict__ Ahi, const unsigned short* __restrict__ Alo,
    const unsigned short* __restrict__ Bhi, const unsigned short* __restrict__ Blo,
    const float* __restrict__ att_src, const float* __restrict__ att_dst,
    float* __restrict__ Z, float* __restrict__ As, float* __restrict__ Ad, int N) {
    constexpr int LD = 40;
    constexpr int WAVES_N = BN / WN;
    constexpr int WAVES_M = 4 / WAVES_N;
    constexpr int WM = BM / WAVES_M;
    constexpr int MW = WM / 32, NW = WN / 32;
    constexpr int H = COLS / 64;
    __shared__ unsigned short sa[2][BM * LD];
    __shared__ unsigned short sb[2][BN * LD];

    const int tid = threadIdx.x;
    const int n0 = blockIdx.x * BM;
    const int c0 = blockIdx.y * BN;
    const int wid = tid >> 6, lane = tid & 63;
    const int wr = wid / WAVES_N, wc = wid % WAVES_N;

    f32x16 acc[MW][NW];
#pragma unroll
    for (int m = 0; m < MW; m++)
#pragma unroll
        for (int n = 0; n < NW; n++)
#pragma unroll
            for (int i = 0; i < 16; i++) acc[m][n][i] = 0.f;

    const int srow = tid >> 2, schk = tid & 3;

    for (int kb = 0; kb < K; kb += 32) {
        __syncthreads();
#pragma unroll
        for (int rr = 0; rr < BM / 64; rr++) {
            const int r = srow + rr * 64;
            const int row = n0 + r;
            short8v vh = {0, 0, 0, 0, 0, 0, 0, 0}, vl = {0, 0, 0, 0, 0, 0, 0, 0};
            if (row < N) {
                vh = *reinterpret_cast<const short8v*>(Ahi + (size_t)row * K + kb + schk * 8);
                vl = *reinterpret_cast<const short8v*>(Alo + (size_t)row * K + kb + schk * 8);
            }
            *reinterpret_cast<short8v*>(&sa[0][r * LD + schk * 8]) = vh;
            *reinterpret_cast<short8v*>(&sa[1][r * LD + schk * 8]) = vl;
        }
#pragma unroll
        for (int rr = 0; rr < BN / 64; rr++) {
            const int cc = srow + rr * 64;
            const short8v vh =
                *reinterpret_cast<const short8v*>(Bhi + (size_t)(c0 + cc) * K + kb + schk * 8);
            const short8v vl =
                *reinterpret_cast<const short8v*>(Blo + (size_t)(c0 + cc) * K + kb + schk * 8);
            *reinterpret_cast<short8v*>(&sb[0][cc * LD + schk * 8]) = vh;
            *reinterpret_cast<short8v*>(&sb[1][cc * LD + schk * 8]) = vl;
        }
        __syncthreads();
#pragma unroll
        for (int ks = 0; ks < 2; ks++) {
            const int koff = ks * 16 + (lane >> 5) * 8;
            short8v ah[MW], al[MW], bh[NW], bl[NW];
#pragma unroll
            for (int m = 0; m < MW; m++) {
                const int ar = wr * WM + m * 32 + (lane & 31);
                ah[m] = *reinterpret_cast<const short8v*>(&sa[0][ar * LD + koff]);
                al[m] = *reinterpret_cast<const short8v*>(&sa[1][ar * LD + koff]);
            }
#pragma unroll
            for (int n = 0; n < NW; n++) {
                const int br = wc * WN + n * 32 + (lane & 31);
                bh[n] = *reinterpret_cast<const short8v*>(&sb[0][br * LD + koff]);
                bl[n] = *reinterpret_cast<const short8v*>(&sb[1][br * LD + koff]);
            }
#pragma unroll
            for (int m = 0; m < MW; m++)
#pragma unroll
                for (int n = 0; n < NW; n++) {
                    acc[m][n] = __builtin_amdgcn_mfma_f32_32x32x16_bf16(ah[m], bh[n], acc[m][n], 0, 0, 0);
                    acc[m][n] = __builtin_amdgcn_mfma_f32_32x32x16_bf16(ah[m], bl[n], acc[m][n], 0, 0, 0);
                    acc[m][n] = __builtin_amdgcn_mfma_f32_32x32x16_bf16(al[m], bh[n], acc[m][n], 0, 0, 0);
                }
        }
    }

    const int colb = c0 + wc * WN + (lane & 31);
    const int rowb = n0 + wr * WM + 4 * (lane >> 5);
#pragma unroll
    for (int m = 0; m < MW; m++)
#pragma unroll
        for (int n = 0; n < NW; n++)
#pragma unroll
            for (int r = 0; r < 16; r++) {
                const int row = rowb + m * 32 + (r & 3) + 8 * (r >> 2);
                if (row < N) Z[(size_t)row * COLS + colb + n * 32] = acc[m][n][r];
            }

    const int hh = (c0 + wc * WN) >> 6;
    float asv[NW], adv[NW];
#pragma unroll
    for (int n = 0; n < NW; n++) {
        asv[n] = att_src[colb + n * 32];
        adv[n] = att_dst[colb + n * 32];
    }
#pragma unroll
    for (int m = 0; m < MW; m++)
#pragma unroll
        for (int r = 0; r < 16; r++) {
            const int row = rowb + m * 32 + (r & 3) + 8 * (r >> 2);
            float ps = 0.f, pd = 0.f;
#pragma unroll
            for (int n = 0; n < NW; n++) {
                ps = fmaf(acc[m][n][r], asv[n], ps);
                pd = fmaf(acc[m][n][r], adv[n], pd);
            }
#pragma unroll
            for (int off = 1; off < 32; off <<= 1) {
                ps += __shfl_xor(ps, off, 64);
                pd += __shfl_xor(pd, off, 64);
            }
            if ((lane & 31) == 0 && row < N) {
                As[(size_t)row * H + hh] = ps;
                Ad[(size_t)row * H + hh] = pd;
            }
        }
}

// ----------------------------- global max pool helpers -----------------------
__device__ __forceinline__ unsigned fenc(float f) {
    unsigned u = __float_as_uint(f);
    return (u & 0x80000000u) ? ~u : (u | 0x80000000u);
}

// ----------------------------- z aggregate (layers 1,2) ----------------------
// Wave per (node, head), inline softmax weights, readlane-broadcast 8-deep
// scalar row gather (best measured structure, R6). OUTMODE 0: bf16 hi/lo
// planes; 1: pooled atomicMax.
template <int H, bool DO_ELU, int OUTMODE>
__global__ __launch_bounds__(256) void k_agg_z(
    const float* __restrict__ Z, const float* __restrict__ As, const float* __restrict__ Ad,
    const int* __restrict__ rowptr, const int* __restrict__ col,
    const float* __restrict__ bias, unsigned short* __restrict__ ohi,
    unsigned short* __restrict__ olo, const int* __restrict__ batch,
    unsigned* __restrict__ enc, int N) {
    constexpr int COLS = H * 64;
    const int tid = threadIdx.x;
    const int wv = tid >> 6;
    const int lane = tid & 63;

    int n, h;
    if constexpr (H == 4) {
        n = blockIdx.x;
        h = wv;
    } else {
        n = blockIdx.x * 4 + wv;
        h = 0;
        if (n >= N) return;
    }

    const int start = rowptr[n];
    const int total = rowptr[n + 1] - start;  // includes self-loop
    const int* __restrict__ cp = col + start;
    const float adn = Ad[(size_t)n * H + h];
    const float* __restrict__ Zc = Z + h * 64 + lane;

    float acc = 0.f, denom = 0.f;

    for (int base = 0; base < total; base += 64) {
        const int cnt = min(64, total - base);
        const int i = base + lane;
        int s = 0;
        float w = 0.f;
        if (i < total) {
            s = cp[i];
            w = __expf(lrelu(As[(size_t)s * H + h] + adn));
        }
        denom += w;

        int jj = 0;
        for (; jj + 8 <= cnt; jj += 8) {
            int sb[8];
            float wb[8], zb[8];
#pragma unroll
            for (int u = 0; u < 8; u++) {
                sb[u] = __builtin_amdgcn_readlane(s, jj + u);
                wb[u] = readlane_f(w, jj + u);
            }
#pragma unroll
            for (int u = 0; u < 8; u++) zb[u] = Zc[(size_t)sb[u] * COLS];
#pragma unroll
            for (int u = 0; u < 8; u++) acc = fmaf(wb[u], zb[u], acc);
        }
        for (; jj + 4 <= cnt; jj += 4) {
            int sb[4];
            float wb[4], zb[4];
#pragma unroll
            for (int u = 0; u < 4; u++) {
                sb[u] = __builtin_amdgcn_readlane(s, jj + u);
                wb[u] = readlane_f(w, jj + u);
            }
#pragma unroll
            for (int u = 0; u < 4; u++) zb[u] = Zc[(size_t)sb[u] * COLS];
#pragma unroll
            for (int u = 0; u < 4; u++) acc = fmaf(wb[u], zb[u], acc);
        }
        for (; jj < cnt; jj++) {
            const int s0 = __builtin_amdgcn_readlane(s, jj);
            const float w0 = readlane_f(w, jj);
            acc = fmaf(w0, Zc[(size_t)s0 * COLS], acc);
        }
    }

#pragma unroll
    for (int off = 1; off < 64; off <<= 1) denom += __shfl_xor(denom, off, 64);

    float ov = acc / (denom + 1e-16f) + bias[h * 64 + lane];
    if (DO_ELU) ov = (ov > 0.f) ? ov : expm1f(ov);

    if constexpr (OUTMODE == 1) {
        const int g = batch[n];
        atomicMax(&enc[g * 64 + lane], fenc(ov));
    } else {
        const unsigned short hb = f2bf(ov);
        ohi[(size_t)n * COLS + h * 64 + lane] = hb;
        olo[(size_t)n * COLS + h * 64 + lane] = f2bf(ov - bf2f(hb));
    }
}

__global__ void k_decode(const unsigned* __restrict__ enc, float* __restrict__ out, int M) {
    int id = blockIdx.x * 256 + threadIdx.x;
    if (id < M) {
        unsigned e = enc[id];
        unsigned u = (e & 0x80000000u) ? (e & 0x7FFFFFFFu) : ~e;
        out[id] = __uint_as_float(u);
    }
}

// ----------------------------- launch ---------------------------------------
extern "C" void kernel_launch(void* const* d_in, const int* in_sizes, int n_in,
                              void* d_out, int out_size, void* d_ws, size_t ws_size,
                              hipStream_t stream) {
    const float* x = (const float*)d_in[0];
    const int* edge_index = (const int*)d_in[1];
    const int* batch = (const int*)d_in[2];
    const float* W0 = (const float*)d_in[3];
    const float* as0 = (const float*)d_in[4];
    const float* ad0 = (const float*)d_in[5];
    const float* b0 = (const float*)d_in[6];
    const float* W1 = (const float*)d_in[7];
    const float* as1 = (const float*)d_in[8];
    const float* ad1 = (const float*)d_in[9];
    const float* b1 = (const float*)d_in[10];
    const float* W2 = (const float*)d_in[11];
    const float* as2 = (const float*)d_in[12];
    const float* ad2 = (const float*)d_in[13];
    const float* b2 = (const float*)d_in[14];

    const int N = in_sizes[0] / 64;  // nodes
    const int E = in_sizes[1] / 2;   // edges (no self-loops)
    const int G = out_size / 64;     // graphs
    const int Et = E + N;            // edges incl. self-loops

    const int* srcs = edge_index;
    const int* dsts = edge_index + E;

    char* p = (char*)d_ws;
    auto alloc = [&](size_t bytes) {
        void* r = (void*)p;
        p += (bytes + 255) & ~(size_t)255;
        return r;
    };
    float* Z = (float*)alloc((size_t)N * 256 * 4);
    unsigned short* Hbhi = (unsigned short*)alloc((size_t)N * 256 * 2);
    unsigned short* Hblo = (unsigned short*)alloc((size_t)N * 256 * 2);
    unsigned short* Axhi = (unsigned short*)alloc((size_t)N * 256 * 2);  // agg_x hi
    unsigned short* Axlo = (unsigned short*)alloc((size_t)N * 256 * 2);  // agg_x lo
    float* As = (float*)alloc((size_t)N * 4 * 4);
    float* Ad = (float*)alloc((size_t)N * 4 * 4);
    int* deg = (int*)alloc((size_t)N * 4);
    int* rowptr = (int*)alloc((size_t)(N + 1) * 4);
    int* cursor = (int*)alloc((size_t)N * 4);
    int* col = (int*)alloc((size_t)Et * 4);
    unsigned short* wt0h = (unsigned short*)alloc(256 * 64 * 2);
    unsigned short* wt0l = (unsigned short*)alloc(256 * 64 * 2);
    unsigned short* wt1h = (unsigned short*)alloc(256 * 256 * 2);
    unsigned short* wt1l = (unsigned short*)alloc(256 * 256 * 2);
    unsigned short* wt2h = (unsigned short*)alloc(64 * 256 * 2);
    unsigned short* wt2l = (unsigned short*)alloc(64 * 256 * 2);
    float* vs0 = (float*)alloc(4 * 64 * 4);
    float* vd0 = (float*)alloc(4 * 64 * 4);
    unsigned* enc = (unsigned*)alloc((size_t)G * 64 * 4);

    hipMemsetAsync(deg, 0, (size_t)N * 4, stream);
    hipMemsetAsync(enc, 0, (size_t)G * 64 * 4, stream);

    const int eb = (E + 255) / 256;
    const int ab = (N + 3) / 4;
    const int gm = (N + 127) / 128;

    k_count<<<eb, 256, 0, stream>>>(dsts, E, deg);
    k_scan<<<1, 1024, 0, stream>>>(deg, rowptr, cursor, N);
    k_scatter<<<(Et + 255) / 256, 256, 0, stream>>>(srcs, dsts, E, N, cursor, col);

    k_wconv<64, 256><<<(64 * 256 + 255) / 256, 256, 0, stream>>>(W0, wt0h, wt0l);
    k_wconv<256, 256><<<(256 * 256 + 255) / 256, 256, 0, stream>>>(W1, wt1h, wt1l);
    k_wconv<256, 64><<<(256 * 64 + 255) / 256, 256, 0, stream>>>(W2, wt2h, wt2l);
    k_attvec<<<1, 64, 0, stream>>>(W0, as0, ad0, vs0, vd0);

    // Layer 0: As0/Ad0 from x; aggregate x; project+bias+ELU (post-GEMM)
    k_att0<<<ab, 256, 0, stream>>>(x, vs0, vd0, As, Ad, N);
    k_aggx<<<ab, 256, 0, stream>>>(x, As, Ad, rowptr, col, Axhi, Axlo, N);
    k_gemm_pe<<<dim3(gm, 4), 256, 0, stream>>>(Axhi, Axlo, wt0h, wt0l, b0, Hbhi, Hblo, N);

    // Layer 1: z GEMM (fused As/Ad) + aggregate
    k_gemm_z<256, 256, 128, 128, 64><<<dim3(gm, 2), 256, 0, stream>>>(
        Hbhi, Hblo, wt1h, wt1l, as1, ad1, Z, As, Ad, N);
    k_agg_z<4, true, 0><<<N, 256, 0, stream>>>(Z, As, Ad, rowptr, col, b1, Hbhi, Hblo,
                                               nullptr, nullptr, N);
    // Layer 2: z GEMM (fused As/Ad) + aggregate + fused pool
    k_gemm_z<256, 64, 128, 64, 64><<<dim3(gm, 1), 256, 0, stream>>>(
        Hbhi, Hblo, wt2h, wt2l, as2, ad2, Z, As, Ad, N);
    k_agg_z<1, false, 1><<<ab, 256, 0, stream>>>(Z, As, Ad, rowptr, col, b2, nullptr, nullptr,
                                                 batch, enc, N);
    k_decode<<<(G * 64 + 255) / 256, 256, 0, stream>>>(enc, (float*)d_out, G * 64);
}

// Round 9
// 509.993 us; speedup vs baseline: 1.3717x; 1.1230x over previous
//
#include <hip/hip_runtime.h>
#include <math.h>

// ---------------------------------------------------------------------------
// GAT encoder: 3 GATConv layers (H=4,4,1) + ELU + global max pool.
// Layer 0: aggregate-then-project (x-row gather serves all 4 heads) + fused
//   post-GEMM (aggx @ W0 + b0, ELU) on matrix cores (bf16x3).
// Layers 1/2: project-then-aggregate; z stored BF16 (halves the XCD-redundant
//   L3->L2 gather stream, the measured bottleneck). Layer-1 aggregate: one
//   wave per node serves ALL 4 heads (ushort4 row gather, uniform-broadcast
//   denominators). Layer-2: per-node wave, bf16 gather, fused atomicMax pool.
// bf16x3 GEMM: fp32 ~ hi+lo bf16; hi*hi+hi*lo+lo*hi MFMA, rel err ~2^-17.
// ---------------------------------------------------------------------------

typedef __attribute__((ext_vector_type(8))) short short8v;
typedef __attribute__((ext_vector_type(16))) float f32x16;

__device__ __forceinline__ float lrelu(float x) { return x > 0.f ? x : 0.2f * x; }

__device__ __forceinline__ unsigned short f2bf(float x) {  // RNE
    unsigned u = __float_as_uint(x);
    return (unsigned short)((u + 0x7FFFu + ((u >> 16) & 1u)) >> 16);
}
__device__ __forceinline__ float bf2f(unsigned short h) {
    return __uint_as_float(((unsigned)h) << 16);
}
__device__ __forceinline__ float readlane_f(float v, int l) {
    return __uint_as_float((unsigned)__builtin_amdgcn_readlane((int)__float_as_uint(v), l));
}

// ----------------------------- CSR build -----------------------------------
__global__ void k_count(const int* __restrict__ dst, int E, int* __restrict__ deg) {
    int e = blockIdx.x * 256 + threadIdx.x;
    if (e < E) atomicAdd(&deg[dst[e]], 1);
}

// rowptr/cursor include +1 slot per node for the self-loop
__global__ void k_scan(const int* __restrict__ deg, int* __restrict__ rowptr,
                       int* __restrict__ cursor, int N) {
    __shared__ int sums[1024];
    const int t = threadIdx.x;
    const int per = (N + 1023) >> 10;
    const int b0 = t * per;
    const int b1 = min(b0 + per, N);
    int s = 0;
    for (int i = b0; i < b1; i++) s += deg[i] + 1;
    sums[t] = s;
    __syncthreads();
    for (int off = 1; off < 1024; off <<= 1) {
        int v = (t >= off) ? sums[t - off] : 0;
        __syncthreads();
        sums[t] += v;
        __syncthreads();
    }
    int run = (t == 0) ? 0 : sums[t - 1];
    for (int i = b0; i < b1; i++) {
        rowptr[i] = run;
        cursor[i] = run;
        run += deg[i] + 1;
    }
    if (t == 1023) rowptr[N] = sums[1023];
}

// edges AND self-loops in one pass
__global__ void k_scatter(const int* __restrict__ src, const int* __restrict__ dst, int E,
                          int N, int* __restrict__ cursor, int* __restrict__ col) {
    int e = blockIdx.x * 256 + threadIdx.x;
    if (e < E) {
        int d = dst[e];
        int p = atomicAdd(&cursor[d], 1);
        col[p] = src[e];
    } else if (e < E + N) {
        int n = e - E;
        int p = atomicAdd(&cursor[n], 1);
        col[p] = n;
    }
}

// ----------------------------- weight converts -------------------------------
// W[k][C] -> Wt hi/lo [C][K]
template <int K, int C>
__global__ void k_wconv(const float* __restrict__ W, unsigned short* __restrict__ thi,
                        unsigned short* __restrict__ tlo) {
    int i = blockIdx.x * 256 + threadIdx.x;
    if (i < K * C) {
        int c = i / K, k = i % K;
        float x = W[(size_t)k * C + c];
        unsigned short h = f2bf(x);
        thi[i] = h;
        tlo[i] = f2bf(x - bf2f(h));
    }
}

// vs[h][k] = sum_c W0[k][h*64+c]*att_src[h][c]; vd likewise (layer 0 only)
__global__ void k_attvec(const float* __restrict__ W, const float* __restrict__ as,
                         const float* __restrict__ ad, float* __restrict__ vs,
                         float* __restrict__ vd) {
    int k = threadIdx.x;
    if (k >= 64) return;
    for (int h = 0; h < 4; h++) {
        float s = 0.f, d = 0.f;
        for (int c = 0; c < 64; c++) {
            float w = W[(size_t)k * 256 + h * 64 + c];
            s = fmaf(w, as[h * 64 + c], s);
            d = fmaf(w, ad[h * 64 + c], d);
        }
        vs[h * 64 + k] = s;
        vd[h * 64 + k] = d;
    }
}

// As0[n,h] = x[n,:] . vs0[h,:]  (wave per node)
__global__ __launch_bounds__(256) void k_att0(
    const float* __restrict__ X, const float* __restrict__ vs, const float* __restrict__ vd,
    float* __restrict__ As, float* __restrict__ Ad, int N) {
    const int n = blockIdx.x * 4 + (threadIdx.x >> 6);
    const int lane = threadIdx.x & 63;
    if (n >= N) return;
    const float xv = X[(size_t)n * 64 + lane];
#pragma unroll
    for (int h = 0; h < 4; h++) {
        float ps = xv * vs[h * 64 + lane];
        float pd = xv * vd[h * 64 + lane];
#pragma unroll
        for (int off = 1; off < 64; off <<= 1) {
            ps += __shfl_xor(ps, off, 64);
            pd += __shfl_xor(pd, off, 64);
        }
        if (lane == 0) {
            As[(size_t)n * 4 + h] = ps;
            Ad[(size_t)n * 4 + h] = pd;
        }
    }
}

// ----------------------------- layer-0 x-aggregate ---------------------------
// Wave per node, lane = x-dim. One 256B x-row gather per edge serves all 4
// heads. Output: normalized agg_x as bf16 hi/lo planes [N][4*64] (head-major).
__global__ __launch_bounds__(256) void k_aggx(
    const float* __restrict__ X, const float* __restrict__ As, const float* __restrict__ Ad,
    const int* __restrict__ rowptr, const int* __restrict__ col,
    unsigned short* __restrict__ ohi, unsigned short* __restrict__ olo, int N) {
    const int n = blockIdx.x * 4 + (threadIdx.x >> 6);
    const int lane = threadIdx.x & 63;
    if (n >= N) return;

    const int start = rowptr[n];
    const int total = rowptr[n + 1] - start;  // includes self-loop
    const int* __restrict__ cp = col + start;
    const float4 adn = *reinterpret_cast<const float4*>(Ad + (size_t)n * 4);

    float a0 = 0.f, a1 = 0.f, a2 = 0.f, a3 = 0.f;
    float d0 = 0.f, d1 = 0.f, d2 = 0.f, d3 = 0.f;

    for (int base = 0; base < total; base += 64) {
        const int cnt = min(64, total - base);
        const int i = base + lane;
        int s = 0;
        float4 w = make_float4(0.f, 0.f, 0.f, 0.f);
        if (i < total) {
            s = cp[i];
            const float4 av = *reinterpret_cast<const float4*>(As + (size_t)s * 4);
            w.x = __expf(lrelu(av.x + adn.x));
            w.y = __expf(lrelu(av.y + adn.y));
            w.z = __expf(lrelu(av.z + adn.z));
            w.w = __expf(lrelu(av.w + adn.w));
        }

        int jj = 0;
        for (; jj + 4 <= cnt; jj += 4) {
            int sb[4];
            float w0[4], w1[4], w2[4], w3[4], xv[4];
#pragma unroll
            for (int u = 0; u < 4; u++) {
                sb[u] = __builtin_amdgcn_readlane(s, jj + u);
                w0[u] = readlane_f(w.x, jj + u);
                w1[u] = readlane_f(w.y, jj + u);
                w2[u] = readlane_f(w.z, jj + u);
                w3[u] = readlane_f(w.w, jj + u);
            }
#pragma unroll
            for (int u = 0; u < 4; u++) xv[u] = X[(size_t)sb[u] * 64 + lane];
#pragma unroll
            for (int u = 0; u < 4; u++) {
                a0 = fmaf(w0[u], xv[u], a0);
                a1 = fmaf(w1[u], xv[u], a1);
                a2 = fmaf(w2[u], xv[u], a2);
                a3 = fmaf(w3[u], xv[u], a3);
                d0 += w0[u]; d1 += w1[u]; d2 += w2[u]; d3 += w3[u];
            }
        }
        for (; jj < cnt; jj++) {
            const int s0 = __builtin_amdgcn_readlane(s, jj);
            const float xv = X[(size_t)s0 * 64 + lane];
            const float e0 = readlane_f(w.x, jj), e1 = readlane_f(w.y, jj);
            const float e2 = readlane_f(w.z, jj), e3 = readlane_f(w.w, jj);
            a0 = fmaf(e0, xv, a0);
            a1 = fmaf(e1, xv, a1);
            a2 = fmaf(e2, xv, a2);
            a3 = fmaf(e3, xv, a3);
            d0 += e0; d1 += e1; d2 += e2; d3 += e3;
        }
    }

    const float o[4] = {a0 / (d0 + 1e-16f), a1 / (d1 + 1e-16f),
                        a2 / (d2 + 1e-16f), a3 / (d3 + 1e-16f)};
#pragma unroll
    for (int h = 0; h < 4; h++) {
        const unsigned short hb = f2bf(o[h]);
        ohi[(size_t)n * 256 + h * 64 + lane] = hb;
        olo[(size_t)n * 256 + h * 64 + lane] = f2bf(o[h] - bf2f(hb));
    }
}

// ----------------------------- post-GEMM (layer 0) ---------------------------
// Hb[n, h*64+c] = ELU(aggx[n, h*64+:64] @ W0[:, h*64+c] + b0[h*64+c]).
__global__ __launch_bounds__(256) void k_gemm_pe(
    const unsigned short* __restrict__ Ahi, const unsigned short* __restrict__ Alo,
    const unsigned short* __restrict__ Bhi, const unsigned short* __restrict__ Blo,
    const float* __restrict__ bias, unsigned short* __restrict__ Ohi,
    unsigned short* __restrict__ Olo, int N) {
    constexpr int LD = 40, BM = 128, K = 64;
    __shared__ unsigned short sa[2][BM * LD];
    __shared__ unsigned short sb[2][64 * LD];

    const int tid = threadIdx.x;
    const int n0 = blockIdx.x * BM;
    const int hh = blockIdx.y;
    const int wid = tid >> 6, lane = tid & 63;

    const unsigned short* __restrict__ Ah = Ahi + hh * 64;
    const unsigned short* __restrict__ Al = Alo + hh * 64;
    const unsigned short* __restrict__ Bh = Bhi + hh * 64 * K;
    const unsigned short* __restrict__ Bl = Blo + hh * 64 * K;

    f32x16 acc[2];
#pragma unroll
    for (int n = 0; n < 2; n++)
#pragma unroll
        for (int i = 0; i < 16; i++) acc[n][i] = 0.f;

    const int srow = tid >> 2, schk = tid & 3;

    for (int kb = 0; kb < K; kb += 32) {
        __syncthreads();
#pragma unroll
        for (int rr = 0; rr < 2; rr++) {
            const int r = srow + rr * 64;
            const int row = n0 + r;
            short8v vh = {0, 0, 0, 0, 0, 0, 0, 0}, vl = {0, 0, 0, 0, 0, 0, 0, 0};
            if (row < N) {
                vh = *reinterpret_cast<const short8v*>(Ah + (size_t)row * 256 + kb + schk * 8);
                vl = *reinterpret_cast<const short8v*>(Al + (size_t)row * 256 + kb + schk * 8);
            }
            *reinterpret_cast<short8v*>(&sa[0][r * LD + schk * 8]) = vh;
            *reinterpret_cast<short8v*>(&sa[1][r * LD + schk * 8]) = vl;
        }
        {
            const short8v vh =
                *reinterpret_cast<const short8v*>(Bh + (size_t)srow * K + kb + schk * 8);
            const short8v vl =
                *reinterpret_cast<const short8v*>(Bl + (size_t)srow * K + kb + schk * 8);
            *reinterpret_cast<short8v*>(&sb[0][srow * LD + schk * 8]) = vh;
            *reinterpret_cast<short8v*>(&sb[1][srow * LD + schk * 8]) = vl;
        }
        __syncthreads();
#pragma unroll
        for (int ks = 0; ks < 2; ks++) {
            const int koff = ks * 16 + (lane >> 5) * 8;
            const int ar = wid * 32 + (lane & 31);
            const short8v ah = *reinterpret_cast<const short8v*>(&sa[0][ar * LD + koff]);
            const short8v al = *reinterpret_cast<const short8v*>(&sa[1][ar * LD + koff]);
            short8v bh[2], bl[2];
#pragma unroll
            for (int n = 0; n < 2; n++) {
                const int br = n * 32 + (lane & 31);
                bh[n] = *reinterpret_cast<const short8v*>(&sb[0][br * LD + koff]);
                bl[n] = *reinterpret_cast<const short8v*>(&sb[1][br * LD + koff]);
            }
#pragma unroll
            for (int n = 0; n < 2; n++) {
                acc[n] = __builtin_amdgcn_mfma_f32_32x32x16_bf16(ah, bh[n], acc[n], 0, 0, 0);
                acc[n] = __builtin_amdgcn_mfma_f32_32x32x16_bf16(ah, bl[n], acc[n], 0, 0, 0);
                acc[n] = __builtin_amdgcn_mfma_f32_32x32x16_bf16(al, bh[n], acc[n], 0, 0, 0);
            }
        }
    }

    const int rowb = n0 + wid * 32 + 4 * (lane >> 5);
#pragma unroll
    for (int n = 0; n < 2; n++) {
        const int c = (lane & 31) + n * 32;
        const float bv = bias[hh * 64 + c];
#pragma unroll
        for (int r = 0; r < 16; r++) {
            const int row = rowb + (r & 3) + 8 * (r >> 2);
            if (row < N) {
                float ov = acc[n][r] + bv;
                ov = (ov > 0.f) ? ov : expm1f(ov);
                const unsigned short hb = f2bf(ov);
                Ohi[(size_t)row * 256 + hh * 64 + c] = hb;
                Olo[(size_t)row * 256 + hh * 64 + c] = f2bf(ov - bf2f(hb));
            }
        }
    }
}

// ----------------------------- z GEMM (layers 1,2) ---------------------------
// Zb[N,COLS] (BF16) = X @ W (bf16x3). Epilogue also emits As/Ad = z . att
// (WN=64: each wave owns one head's 64 cols; 32-lane shfl butterfly).
template <int K, int COLS, int BM, int BN, int WN>
__global__ __launch_bounds__(256) void k_gemm_z(
    const unsigned short* __restrict__ Ahi, const unsigned short* __restrict__ Alo,
    const unsigned short* __restrict__ Bhi, const unsigned short* __restrict__ Blo,
    const float* __restrict__ att_src, const float* __restrict__ att_dst,
    unsigned short* __restrict__ Zb, float* __restrict__ As, float* __restrict__ Ad, int N) {
    constexpr int LD = 40;
    constexpr int WAVES_N = BN / WN;
    constexpr int WAVES_M = 4 / WAVES_N;
    constexpr int WM = BM / WAVES_M;
    constexpr int MW = WM / 32, NW = WN / 32;
    constexpr int H = COLS / 64;
    __shared__ unsigned short sa[2][BM * LD];
    __shared__ unsigned short sb[2][BN * LD];

    const int tid = threadIdx.x;
    const int n0 = blockIdx.x * BM;
    const int c0 = blockIdx.y * BN;
    const int wid = tid >> 6, lane = tid & 63;
    const int wr = wid / WAVES_N, wc = wid % WAVES_N;

    f32x16 acc[MW][NW];
#pragma unroll
    for (int m = 0; m < MW; m++)
#pragma unroll
        for (int n = 0; n < NW; n++)
#pragma unroll
            for (int i = 0; i < 16; i++) acc[m][n][i] = 0.f;

    const int srow = tid >> 2, schk = tid & 3;

    for (int kb = 0; kb < K; kb += 32) {
        __syncthreads();
#pragma unroll
        for (int rr = 0; rr < BM / 64; rr++) {
            const int r = srow + rr * 64;
            const int row = n0 + r;
            short8v vh = {0, 0, 0, 0, 0, 0, 0, 0}, vl = {0, 0, 0, 0, 0, 0, 0, 0};
            if (row < N) {
                vh = *reinterpret_cast<const short8v*>(Ahi + (size_t)row * K + kb + schk * 8);
                vl = *reinterpret_cast<const short8v*>(Alo + (size_t)row * K + kb + schk * 8);
            }
            *reinterpret_cast<short8v*>(&sa[0][r * LD + schk * 8]) = vh;
            *reinterpret_cast<short8v*>(&sa[1][r * LD + schk * 8]) = vl;
        }
#pragma unroll
        for (int rr = 0; rr < BN / 64; rr++) {
            const int cc = srow + rr * 64;
            const short8v vh =
                *reinterpret_cast<const short8v*>(Bhi + (size_t)(c0 + cc) * K + kb + schk * 8);
            const short8v vl =
                *reinterpret_cast<const short8v*>(Blo + (size_t)(c0 + cc) * K + kb + schk * 8);
            *reinterpret_cast<short8v*>(&sb[0][cc * LD + schk * 8]) = vh;
            *reinterpret_cast<short8v*>(&sb[1][cc * LD + schk * 8]) = vl;
        }
        __syncthreads();
#pragma unroll
        for (int ks = 0; ks < 2; ks++) {
            const int koff = ks * 16 + (lane >> 5) * 8;
            short8v ah[MW], al[MW], bh[NW], bl[NW];
#pragma unroll
            for (int m = 0; m < MW; m++) {
                const int ar = wr * WM + m * 32 + (lane & 31);
                ah[m] = *reinterpret_cast<const short8v*>(&sa[0][ar * LD + koff]);
                al[m] = *reinterpret_cast<const short8v*>(&sa[1][ar * LD + koff]);
            }
#pragma unroll
            for (int n = 0; n < NW; n++) {
                const int br = wc * WN + n * 32 + (lane & 31);
                bh[n] = *reinterpret_cast<const short8v*>(&sb[0][br * LD + koff]);
                bl[n] = *reinterpret_cast<const short8v*>(&sb[1][br * LD + koff]);
            }
#pragma unroll
            for (int m = 0; m < MW; m++)
#pragma unroll
                for (int n = 0; n < NW; n++) {
                    acc[m][n] = __builtin_amdgcn_mfma_f32_32x32x16_bf16(ah[m], bh[n], acc[m][n], 0, 0, 0);
                    acc[m][n] = __builtin_amdgcn_mfma_f32_32x32x16_bf16(ah[m], bl[n], acc[m][n], 0, 0, 0);
                    acc[m][n] = __builtin_amdgcn_mfma_f32_32x32x16_bf16(al[m], bh[n], acc[m][n], 0, 0, 0);
                }
        }
    }

    const int colb = c0 + wc * WN + (lane & 31);
    const int rowb = n0 + wr * WM + 4 * (lane >> 5);
#pragma unroll
    for (int m = 0; m < MW; m++)
#pragma unroll
        for (int n = 0; n < NW; n++)
#pragma unroll
            for (int r = 0; r < 16; r++) {
                const int row = rowb + m * 32 + (r & 3) + 8 * (r >> 2);
                if (row < N) Zb[(size_t)row * COLS + colb + n * 32] = f2bf(acc[m][n][r]);
            }

    const int hh = (c0 + wc * WN) >> 6;
    float asv[NW], adv[NW];
#pragma unroll
    for (int n = 0; n < NW; n++) {
        asv[n] = att_src[colb + n * 32];
        adv[n] = att_dst[colb + n * 32];
    }
#pragma unroll
    for (int m = 0; m < MW; m++)
#pragma unroll
        for (int r = 0; r < 16; r++) {
            const int row = rowb + m * 32 + (r & 3) + 8 * (r >> 2);
            float ps = 0.f, pd = 0.f;
#pragma unroll
            for (int n = 0; n < NW; n++) {
                ps = fmaf(acc[m][n][r], asv[n], ps);
                pd = fmaf(acc[m][n][r], adv[n], pd);
            }
#pragma unroll
            for (int off = 1; off < 32; off <<= 1) {
                ps += __shfl_xor(ps, off, 64);
                pd += __shfl_xor(pd, off, 64);
            }
            if ((lane & 31) == 0 && row < N) {
                As[(size_t)row * H + hh] = ps;
                Ad[(size_t)row * H + hh] = pd;
            }
        }
}

// ----------------------------- global max pool helpers -----------------------
__device__ __forceinline__ unsigned fenc(float f) {
    unsigned u = __float_as_uint(f);
    return (u & 0x80000000u) ? ~u : (u | 0x80000000u);
}

// ----------------------------- layer-1 aggregate (all heads) -----------------
// One wave per node. Lane: head h = lane>>4, channels (lane&15)*4..+3. Per edge
// ONE ushort4 load covers this lane's 4 bf16 channels (512B/edge wave-wide,
// all 4 heads). Weights via 5 readlane broadcasts; denominators accumulate
// uniformly (no reduction). Output: normalized+bias+ELU bf16 hi/lo planes.
__global__ __launch_bounds__(256) void k_agg4(
    const unsigned short* __restrict__ Zb, const float* __restrict__ As,
    const float* __restrict__ Ad, const int* __restrict__ rowptr,
    const int* __restrict__ col, const float* __restrict__ bias,
    unsigned short* __restrict__ ohi, unsigned short* __restrict__ olo, int N) {
    const int n = blockIdx.x * 4 + (threadIdx.x >> 6);
    const int lane = threadIdx.x & 63;
    if (n >= N) return;
    const int h = lane >> 4;

    const int start = rowptr[n];
    const int total = rowptr[n + 1] - start;  // includes self-loop
    const int* __restrict__ cp = col + start;
    const float4 adn = *reinterpret_cast<const float4*>(Ad + (size_t)n * 4);
    const unsigned short* __restrict__ Zl = Zb + lane * 4;

    float a0 = 0.f, a1 = 0.f, a2 = 0.f, a3 = 0.f;
    float d0 = 0.f, d1 = 0.f, d2 = 0.f, d3 = 0.f;

    for (int base = 0; base < total; base += 64) {
        const int cnt = min(64, total - base);
        const int i = base + lane;
        int s = 0;
        float4 w = make_float4(0.f, 0.f, 0.f, 0.f);
        if (i < total) {
            s = cp[i];
            const float4 av = *reinterpret_cast<const float4*>(As + (size_t)s * 4);
            w.x = __expf(lrelu(av.x + adn.x));
            w.y = __expf(lrelu(av.y + adn.y));
            w.z = __expf(lrelu(av.z + adn.z));
            w.w = __expf(lrelu(av.w + adn.w));
        }

        int jj = 0;
        for (; jj + 8 <= cnt; jj += 8) {
            int sb[8];
            float w0[8], w1[8], w2[8], w3[8];
            ushort4 zb[8];
#pragma unroll
            for (int u = 0; u < 8; u++) {
                sb[u] = __builtin_amdgcn_readlane(s, jj + u);
                w0[u] = readlane_f(w.x, jj + u);
                w1[u] = readlane_f(w.y, jj + u);
                w2[u] = readlane_f(w.z, jj + u);
                w3[u] = readlane_f(w.w, jj + u);
            }
#pragma unroll
            for (int u = 0; u < 8; u++)
                zb[u] = *reinterpret_cast<const ushort4*>(Zl + (size_t)sb[u] * 256);
#pragma unroll
            for (int u = 0; u < 8; u++) {
                const float ws = (h == 0) ? w0[u] : (h == 1) ? w1[u] : (h == 2) ? w2[u] : w3[u];
                a0 = fmaf(ws, bf2f(zb[u].x), a0);
                a1 = fmaf(ws, bf2f(zb[u].y), a1);
                a2 = fmaf(ws, bf2f(zb[u].z), a2);
                a3 = fmaf(ws, bf2f(zb[u].w), a3);
                d0 += w0[u]; d1 += w1[u]; d2 += w2[u]; d3 += w3[u];
            }
        }
        for (; jj + 4 <= cnt; jj += 4) {
            int sb[4];
            float w0[4], w1[4], w2[4], w3[4];
            ushort4 zb[4];
#pragma unroll
            for (int u = 0; u < 4; u++) {
                sb[u] = __builtin_amdgcn_readlane(s, jj + u);
                w0[u] = readlane_f(w.x, jj + u);
                w1[u] = readlane_f(w.y, jj + u);
                w2[u] = readlane_f(w.z, jj + u);
                w3[u] = readlane_f(w.w, jj + u);
            }
#pragma unroll
            for (int u = 0; u < 4; u++)
                zb[u] = *reinterpret_cast<const ushort4*>(Zl + (size_t)sb[u] * 256);
#pragma unroll
            for (int u = 0; u < 4; u++) {
                const float ws = (h == 0) ? w0[u] : (h == 1) ? w1[u] : (h == 2) ? w2[u] : w3[u];
                a0 = fmaf(ws, bf2f(zb[u].x), a0);
                a1 = fmaf(ws, bf2f(zb[u].y), a1);
                a2 = fmaf(ws, bf2f(zb[u].z), a2);
                a3 = fmaf(ws, bf2f(zb[u].w), a3);
                d0 += w0[u]; d1 += w1[u]; d2 += w2[u]; d3 += w3[u];
            }
        }
        for (; jj < cnt; jj++) {
            const int s0 = __builtin_amdgcn_readlane(s, jj);
            const float e0 = readlane_f(w.x, jj), e1 = readlane_f(w.y, jj);
            const float e2 = readlane_f(w.z, jj), e3 = readlane_f(w.w, jj);
            const ushort4 zb = *reinterpret_cast<const ushort4*>(Zl + (size_t)s0 * 256);
            const float ws = (h == 0) ? e0 : (h == 1) ? e1 : (h == 2) ? e2 : e3;
            a0 = fmaf(ws, bf2f(zb.x), a0);
            a1 = fmaf(ws, bf2f(zb.y), a1);
            a2 = fmaf(ws, bf2f(zb.z), a2);
            a3 = fmaf(ws, bf2f(zb.w), a3);
            d0 += e0; d1 += e1; d2 += e2; d3 += e3;
        }
    }

    const float den = (h == 0) ? d0 : (h == 1) ? d1 : (h == 2) ? d2 : d3;
    const float inv = 1.f / (den + 1e-16f);
    float o[4] = {a0, a1, a2, a3};
    ushort4 vh, vl;
#pragma unroll
    for (int j = 0; j < 4; j++) {
        float ov = o[j] * inv + bias[lane * 4 + j];
        ov = (ov > 0.f) ? ov : expm1f(ov);
        o[j] = ov;
    }
    const unsigned short b0 = f2bf(o[0]), b1 = f2bf(o[1]), b2 = f2bf(o[2]), b3 = f2bf(o[3]);
    vh = make_ushort4(b0, b1, b2, b3);
    vl = make_ushort4(f2bf(o[0] - bf2f(b0)), f2bf(o[1] - bf2f(b1)),
                      f2bf(o[2] - bf2f(b2)), f2bf(o[3] - bf2f(b3)));
    *reinterpret_cast<ushort4*>(ohi + (size_t)n * 256 + lane * 4) = vh;
    *reinterpret_cast<ushort4*>(olo + (size_t)n * 256 + lane * 4) = vl;
}

// ----------------------------- layer-2 aggregate + pool ----------------------
// Wave per node (H=1). Lane = channel; bf16 z gather (128B/edge), uniform
// denom via broadcast weights, fused encoded atomicMax pool.
__global__ __launch_bounds__(256) void k_agg1(
    const unsigned short* __restrict__ Zb, const float* __restrict__ As,
    const float* __restrict__ Ad, const int* __restrict__ rowptr,
    const int* __restrict__ col, const float* __restrict__ bias,
    const int* __restrict__ batch, unsigned* __restrict__ enc, int N) {
    const int n = blockIdx.x * 4 + (threadIdx.x >> 6);
    const int lane = threadIdx.x & 63;
    if (n >= N) return;

    const int start = rowptr[n];
    const int total = rowptr[n + 1] - start;  // includes self-loop
    const int* __restrict__ cp = col + start;
    const float adn = Ad[n];

    float acc = 0.f, denom = 0.f;

    for (int base = 0; base < total; base += 64) {
        const int cnt = min(64, total - base);
        const int i = base + lane;
        int s = 0;
        float w = 0.f;
        if (i < total) {
            s = cp[i];
            w = __expf(lrelu(As[s] + adn));
        }

        int jj = 0;
        for (; jj + 8 <= cnt; jj += 8) {
            int sb[8];
            float wb[8], zb[8];
#pragma unroll
            for (int u = 0; u < 8; u++) {
                sb[u] = __builtin_amdgcn_readlane(s, jj + u);
                wb[u] = readlane_f(w, jj + u);
            }
#pragma unroll
            for (int u = 0; u < 8; u++) zb[u] = bf2f(Zb[(size_t)sb[u] * 64 + lane]);
#pragma unroll
            for (int u = 0; u < 8; u++) {
                acc = fmaf(wb[u], zb[u], acc);
                denom += wb[u];
            }
        }
        for (; jj < cnt; jj++) {
            const int s0 = __builtin_amdgcn_readlane(s, jj);
            const float w0 = readlane_f(w, jj);
            acc = fmaf(w0, bf2f(Zb[(size_t)s0 * 64 + lane]), acc);
            denom += w0;
        }
    }

    const float ov = acc / (denom + 1e-16f) + bias[lane];
    const int g = batch[n];
    atomicMax(&enc[g * 64 + lane], fenc(ov));
}

__global__ void k_decode(const unsigned* __restrict__ enc, float* __restrict__ out, int M) {
    int id = blockIdx.x * 256 + threadIdx.x;
    if (id < M) {
        unsigned e = enc[id];
        unsigned u = (e & 0x80000000u) ? (e & 0x7FFFFFFFu) : ~e;
        out[id] = __uint_as_float(u);
    }
}

// ----------------------------- launch ---------------------------------------
extern "C" void kernel_launch(void* const* d_in, const int* in_sizes, int n_in,
                              void* d_out, int out_size, void* d_ws, size_t ws_size,
                              hipStream_t stream) {
    const float* x = (const float*)d_in[0];
    const int* edge_index = (const int*)d_in[1];
    const int* batch = (const int*)d_in[2];
    const float* W0 = (const float*)d_in[3];
    const float* as0 = (const float*)d_in[4];
    const float* ad0 = (const float*)d_in[5];
    const float* b0 = (const float*)d_in[6];
    const float* W1 = (const float*)d_in[7];
    const float* as1 = (const float*)d_in[8];
    const float* ad1 = (const float*)d_in[9];
    const float* b1 = (const float*)d_in[10];
    const float* W2 = (const float*)d_in[11];
    const float* as2 = (const float*)d_in[12];
    const float* ad2 = (const float*)d_in[13];
    const float* b2 = (const float*)d_in[14];

    const int N = in_sizes[0] / 64;  // nodes
    const int E = in_sizes[1] / 2;   // edges (no self-loops)
    const int G = out_size / 64;     // graphs
    const int Et = E + N;            // edges incl. self-loops

    const int* srcs = edge_index;
    const int* dsts = edge_index + E;

    char* p = (char*)d_ws;
    auto alloc = [&](size_t bytes) {
        void* r = (void*)p;
        p += (bytes + 255) & ~(size_t)255;
        return r;
    };
    unsigned short* Zb = (unsigned short*)alloc((size_t)N * 256 * 2);  // bf16 z
    unsigned short* Hbhi = (unsigned short*)alloc((size_t)N * 256 * 2);
    unsigned short* Hblo = (unsigned short*)alloc((size_t)N * 256 * 2);
    unsigned short* Axhi = (unsigned short*)alloc((size_t)N * 256 * 2);
    unsigned short* Axlo = (unsigned short*)alloc((size_t)N * 256 * 2);
    float* As = (float*)alloc((size_t)N * 4 * 4);
    float* Ad = (float*)alloc((size_t)N * 4 * 4);
    int* deg = (int*)alloc((size_t)N * 4);
    int* rowptr = (int*)alloc((size_t)(N + 1) * 4);
    int* cursor = (int*)alloc((size_t)N * 4);
    int* col = (int*)alloc((size_t)Et * 4);
    unsigned short* wt0h = (unsigned short*)alloc(256 * 64 * 2);
    unsigned short* wt0l = (unsigned short*)alloc(256 * 64 * 2);
    unsigned short* wt1h = (unsigned short*)alloc(256 * 256 * 2);
    unsigned short* wt1l = (unsigned short*)alloc(256 * 256 * 2);
    unsigned short* wt2h = (unsigned short*)alloc(64 * 256 * 2);
    unsigned short* wt2l = (unsigned short*)alloc(64 * 256 * 2);
    float* vs0 = (float*)alloc(4 * 64 * 4);
    float* vd0 = (float*)alloc(4 * 64 * 4);
    unsigned* enc = (unsigned*)alloc((size_t)G * 64 * 4);

    hipMemsetAsync(deg, 0, (size_t)N * 4, stream);
    hipMemsetAsync(enc, 0, (size_t)G * 64 * 4, stream);

    const int eb = (E + 255) / 256;
    const int ab = (N + 3) / 4;
    const int gm = (N + 127) / 128;

    k_count<<<eb, 256, 0, stream>>>(dsts, E, deg);
    k_scan<<<1, 1024, 0, stream>>>(deg, rowptr, cursor, N);
    k_scatter<<<(Et + 255) / 256, 256, 0, stream>>>(srcs, dsts, E, N, cursor, col);

    k_wconv<64, 256><<<(64 * 256 + 255) / 256, 256, 0, stream>>>(W0, wt0h, wt0l);
    k_wconv<256, 256><<<(256 * 256 + 255) / 256, 256, 0, stream>>>(W1, wt1h, wt1l);
    k_wconv<256, 64><<<(256 * 64 + 255) / 256, 256, 0, stream>>>(W2, wt2h, wt2l);
    k_attvec<<<1, 64, 0, stream>>>(W0, as0, ad0, vs0, vd0);

    // Layer 0: As0/Ad0 from x; aggregate x; project+bias+ELU (post-GEMM)
    k_att0<<<ab, 256, 0, stream>>>(x, vs0, vd0, As, Ad, N);
    k_aggx<<<ab, 256, 0, stream>>>(x, As, Ad, rowptr, col, Axhi, Axlo, N);
    k_gemm_pe<<<dim3(gm, 4), 256, 0, stream>>>(Axhi, Axlo, wt0h, wt0l, b0, Hbhi, Hblo, N);

    // Layer 1: z GEMM (bf16 out, fused As/Ad) + all-heads aggregate
    k_gemm_z<256, 256, 128, 128, 64><<<dim3(gm, 2), 256, 0, stream>>>(
        Hbhi, Hblo, wt1h, wt1l, as1, ad1, Zb, As, Ad, N);
    k_agg4<<<ab, 256, 0, stream>>>(Zb, As, Ad, rowptr, col, b1, Hbhi, Hblo, N);

    // Layer 2: z GEMM (bf16 out, fused As/Ad) + aggregate + fused pool
    k_gemm_z<256, 64, 128, 64, 64><<<dim3(gm, 1), 256, 0, stream>>>(
        Hbhi, Hblo, wt2h, wt2l, as2, ad2, Zb, As, Ad, N);
    k_agg1<<<ab, 256, 0, stream>>>(Zb, As, Ad, rowptr, col, b2, batch, enc, N);
    k_decode<<<(G * 64 + 255) / 256, 256, 0, stream>>>(enc, (float*)d_out, G * 64);
}

// Round 10
// 401.297 us; speedup vs baseline: 1.7432x; 1.2709x over previous
//
#include <hip/hip_runtime.h>
#include <math.h>

// ---------------------------------------------------------------------------
// GAT encoder: 3 GATConv layers (H=4,4,1) + ELU + global max pool.
// Layer 0: aggregate-then-project (x-row gather serves all 4 heads) + fused
//   post-GEMM (aggx @ W0 + b0, ELU) on matrix cores (bf16x3).
// Layers 1/2: project-then-aggregate; z stored BF16 (halves the XCD-redundant
//   L3->L2 gather stream). Layer-1 aggregate: one wave per node serves ALL 4
//   heads. Layer-2: per-node wave, bf16 gather, fused atomicMax pool.
// CSR build uses a hierarchical 3-pass parallel scan (the old single-block
// scan was a hidden 110us serial kernel).
// bf16x3 GEMM: fp32 ~ hi+lo bf16; hi*hi+hi*lo+lo*hi MFMA, rel err ~2^-17.
// ---------------------------------------------------------------------------

typedef __attribute__((ext_vector_type(8))) short short8v;
typedef __attribute__((ext_vector_type(16))) float f32x16;

__device__ __forceinline__ float lrelu(float x) { return x > 0.f ? x : 0.2f * x; }

__device__ __forceinline__ unsigned short f2bf(float x) {  // RNE
    unsigned u = __float_as_uint(x);
    return (unsigned short)((u + 0x7FFFu + ((u >> 16) & 1u)) >> 16);
}
__device__ __forceinline__ float bf2f(unsigned short h) {
    return __uint_as_float(((unsigned)h) << 16);
}
__device__ __forceinline__ float readlane_f(float v, int l) {
    return __uint_as_float((unsigned)__builtin_amdgcn_readlane((int)__float_as_uint(v), l));
}

// ----------------------------- CSR build -----------------------------------
__global__ void k_count(const int* __restrict__ dst, int E, int* __restrict__ deg) {
    int e = blockIdx.x * 256 + threadIdx.x;
    if (e < E) atomicAdd(&deg[dst[e]], 1);
}

// Pass 1: per-block inclusive scan of (deg[i]+1); write local prefix + block sum
__global__ __launch_bounds__(256) void k_scan1(const int* __restrict__ deg,
                                               int* __restrict__ incl,
                                               int* __restrict__ bsum, int N) {
    const int i = blockIdx.x * 256 + threadIdx.x;
    const int lane = threadIdx.x & 63;
    const int wv = threadIdx.x >> 6;
    int sc = (i < N) ? deg[i] + 1 : 0;
#pragma unroll
    for (int off = 1; off < 64; off <<= 1) {
        int t = __shfl_up(sc, off, 64);
        if (lane >= off) sc += t;
    }
    __shared__ int wsum[4];
    if (lane == 63) wsum[wv] = sc;
    __syncthreads();
    int woff = 0;
#pragma unroll
    for (int k = 0; k < 3; k++)
        if (wv > k) woff += wsum[k];
    sc += woff;
    if (i < N) incl[i] = sc;
    if (threadIdx.x == 255) bsum[blockIdx.x] = sc;  // OOB lanes contribute 0
}

// Pass 2: single block inclusive scan of block sums (nb <= 1024)
__global__ __launch_bounds__(1024) void k_scan2(int* __restrict__ bsum, int nb) {
    const int t = threadIdx.x;
    const int lane = t & 63;
    const int wv = t >> 6;
    int sc = (t < nb) ? bsum[t] : 0;
#pragma unroll
    for (int off = 1; off < 64; off <<= 1) {
        int u = __shfl_up(sc, off, 64);
        if (lane >= off) sc += u;
    }
    __shared__ int wsum[16];
    if (lane == 63) wsum[wv] = sc;
    __syncthreads();
    int woff = 0;
#pragma unroll
    for (int k = 0; k < 15; k++)
        if (wv > k) woff += wsum[k];
    sc += woff;
    if (t < nb) bsum[t] = sc;
}

// Pass 3: exclusive global offsets -> rowptr/cursor; rowptr[N] = total
__global__ void k_scan3(const int* __restrict__ deg, const int* __restrict__ incl,
                        const int* __restrict__ bsum, int* __restrict__ rowptr,
                        int* __restrict__ cursor, int N, int nb) {
    int i = blockIdx.x * 256 + threadIdx.x;
    if (i < N) {
        const int off = (blockIdx.x > 0) ? bsum[blockIdx.x - 1] : 0;
        const int excl = incl[i] + off - (deg[i] + 1);
        rowptr[i] = excl;
        cursor[i] = excl;
        if (i == N - 1) rowptr[N] = bsum[nb - 1];
    }
}

// edges AND self-loops in one pass
__global__ void k_scatter(const int* __restrict__ src, const int* __restrict__ dst, int E,
                          int N, int* __restrict__ cursor, int* __restrict__ col) {
    int e = blockIdx.x * 256 + threadIdx.x;
    if (e < E) {
        int d = dst[e];
        int p = atomicAdd(&cursor[d], 1);
        col[p] = src[e];
    } else if (e < E + N) {
        int n = e - E;
        int p = atomicAdd(&cursor[n], 1);
        col[p] = n;
    }
}

// ----------------------------- weight converts -------------------------------
// W[k][C] -> Wt hi/lo [C][K]
template <int K, int C>
__global__ void k_wconv(const float* __restrict__ W, unsigned short* __restrict__ thi,
                        unsigned short* __restrict__ tlo) {
    int i = blockIdx.x * 256 + threadIdx.x;
    if (i < K * C) {
        int c = i / K, k = i % K;
        float x = W[(size_t)k * C + c];
        unsigned short h = f2bf(x);
        thi[i] = h;
        tlo[i] = f2bf(x - bf2f(h));
    }
}

// vs[h][k] = sum_c W0[k][h*64+c]*att_src[h][c]; vd likewise (layer 0 only)
__global__ void k_attvec(const float* __restrict__ W, const float* __restrict__ as,
                         const float* __restrict__ ad, float* __restrict__ vs,
                         float* __restrict__ vd) {
    int k = threadIdx.x;
    if (k >= 64) return;
    for (int h = 0; h < 4; h++) {
        float s = 0.f, d = 0.f;
        for (int c = 0; c < 64; c++) {
            float w = W[(size_t)k * 256 + h * 64 + c];
            s = fmaf(w, as[h * 64 + c], s);
            d = fmaf(w, ad[h * 64 + c], d);
        }
        vs[h * 64 + k] = s;
        vd[h * 64 + k] = d;
    }
}

// As0[n,h] = x[n,:] . vs0[h,:]  (wave per node)
__global__ __launch_bounds__(256) void k_att0(
    const float* __restrict__ X, const float* __restrict__ vs, const float* __restrict__ vd,
    float* __restrict__ As, float* __restrict__ Ad, int N) {
    const int n = blockIdx.x * 4 + (threadIdx.x >> 6);
    const int lane = threadIdx.x & 63;
    if (n >= N) return;
    const float xv = X[(size_t)n * 64 + lane];
#pragma unroll
    for (int h = 0; h < 4; h++) {
        float ps = xv * vs[h * 64 + lane];
        float pd = xv * vd[h * 64 + lane];
#pragma unroll
        for (int off = 1; off < 64; off <<= 1) {
            ps += __shfl_xor(ps, off, 64);
            pd += __shfl_xor(pd, off, 64);
        }
        if (lane == 0) {
            As[(size_t)n * 4 + h] = ps;
            Ad[(size_t)n * 4 + h] = pd;
        }
    }
}

// ----------------------------- layer-0 x-aggregate ---------------------------
// Wave per node, lane = x-dim. One 256B x-row gather per edge serves all 4
// heads. Output: normalized agg_x as bf16 hi/lo planes [N][4*64] (head-major).
__global__ __launch_bounds__(256) void k_aggx(
    const float* __restrict__ X, const float* __restrict__ As, const float* __restrict__ Ad,
    const int* __restrict__ rowptr, const int* __restrict__ col,
    unsigned short* __restrict__ ohi, unsigned short* __restrict__ olo, int N) {
    const int n = blockIdx.x * 4 + (threadIdx.x >> 6);
    const int lane = threadIdx.x & 63;
    if (n >= N) return;

    const int start = rowptr[n];
    const int total = rowptr[n + 1] - start;  // includes self-loop
    const int* __restrict__ cp = col + start;
    const float4 adn = *reinterpret_cast<const float4*>(Ad + (size_t)n * 4);

    float a0 = 0.f, a1 = 0.f, a2 = 0.f, a3 = 0.f;
    float d0 = 0.f, d1 = 0.f, d2 = 0.f, d3 = 0.f;

    for (int base = 0; base < total; base += 64) {
        const int cnt = min(64, total - base);
        const int i = base + lane;
        int s = 0;
        float4 w = make_float4(0.f, 0.f, 0.f, 0.f);
        if (i < total) {
            s = cp[i];
            const float4 av = *reinterpret_cast<const float4*>(As + (size_t)s * 4);
            w.x = __expf(lrelu(av.x + adn.x));
            w.y = __expf(lrelu(av.y + adn.y));
            w.z = __expf(lrelu(av.z + adn.z));
            w.w = __expf(lrelu(av.w + adn.w));
        }

        int jj = 0;
        for (; jj + 4 <= cnt; jj += 4) {
            int sb[4];
            float w0[4], w1[4], w2[4], w3[4], xv[4];
#pragma unroll
            for (int u = 0; u < 4; u++) {
                sb[u] = __builtin_amdgcn_readlane(s, jj + u);
                w0[u] = readlane_f(w.x, jj + u);
                w1[u] = readlane_f(w.y, jj + u);
                w2[u] = readlane_f(w.z, jj + u);
                w3[u] = readlane_f(w.w, jj + u);
            }
#pragma unroll
            for (int u = 0; u < 4; u++) xv[u] = X[(size_t)sb[u] * 64 + lane];
#pragma unroll
            for (int u = 0; u < 4; u++) {
                a0 = fmaf(w0[u], xv[u], a0);
                a1 = fmaf(w1[u], xv[u], a1);
                a2 = fmaf(w2[u], xv[u], a2);
                a3 = fmaf(w3[u], xv[u], a3);
                d0 += w0[u]; d1 += w1[u]; d2 += w2[u]; d3 += w3[u];
            }
        }
        for (; jj < cnt; jj++) {
            const int s0 = __builtin_amdgcn_readlane(s, jj);
            const float xv = X[(size_t)s0 * 64 + lane];
            const float e0 = readlane_f(w.x, jj), e1 = readlane_f(w.y, jj);
            const float e2 = readlane_f(w.z, jj), e3 = readlane_f(w.w, jj);
            a0 = fmaf(e0, xv, a0);
            a1 = fmaf(e1, xv, a1);
            a2 = fmaf(e2, xv, a2);
            a3 = fmaf(e3, xv, a3);
            d0 += e0; d1 += e1; d2 += e2; d3 += e3;
        }
    }

    const float o[4] = {a0 / (d0 + 1e-16f), a1 / (d1 + 1e-16f),
                        a2 / (d2 + 1e-16f), a3 / (d3 + 1e-16f)};
#pragma unroll
    for (int h = 0; h < 4; h++) {
        const unsigned short hb = f2bf(o[h]);
        ohi[(size_t)n * 256 + h * 64 + lane] = hb;
        olo[(size_t)n * 256 + h * 64 + lane] = f2bf(o[h] - bf2f(hb));
    }
}

// ----------------------------- post-GEMM (layer 0) ---------------------------
// Hb[n, h*64+c] = ELU(aggx[n, h*64+:64] @ W0[:, h*64+c] + b0[h*64+c]).
__global__ __launch_bounds__(256) void k_gemm_pe(
    const unsigned short* __restrict__ Ahi, const unsigned short* __restrict__ Alo,
    const unsigned short* __restrict__ Bhi, const unsigned short* __restrict__ Blo,
    const float* __restrict__ bias, unsigned short* __restrict__ Ohi,
    unsigned short* __restrict__ Olo, int N) {
    constexpr int LD = 40, BM = 128, K = 64;
    __shared__ unsigned short sa[2][BM * LD];
    __shared__ unsigned short sb[2][64 * LD];

    const int tid = threadIdx.x;
    const int n0 = blockIdx.x * BM;
    const int hh = blockIdx.y;
    const int wid = tid >> 6, lane = tid & 63;

    const unsigned short* __restrict__ Ah = Ahi + hh * 64;
    const unsigned short* __restrict__ Al = Alo + hh * 64;
    const unsigned short* __restrict__ Bh = Bhi + hh * 64 * K;
    const unsigned short* __restrict__ Bl = Blo + hh * 64 * K;

    f32x16 acc[2];
#pragma unroll
    for (int n = 0; n < 2; n++)
#pragma unroll
        for (int i = 0; i < 16; i++) acc[n][i] = 0.f;

    const int srow = tid >> 2, schk = tid & 3;

    for (int kb = 0; kb < K; kb += 32) {
        __syncthreads();
#pragma unroll
        for (int rr = 0; rr < 2; rr++) {
            const int r = srow + rr * 64;
            const int row = n0 + r;
            short8v vh = {0, 0, 0, 0, 0, 0, 0, 0}, vl = {0, 0, 0, 0, 0, 0, 0, 0};
            if (row < N) {
                vh = *reinterpret_cast<const short8v*>(Ah + (size_t)row * 256 + kb + schk * 8);
                vl = *reinterpret_cast<const short8v*>(Al + (size_t)row * 256 + kb + schk * 8);
            }
            *reinterpret_cast<short8v*>(&sa[0][r * LD + schk * 8]) = vh;
            *reinterpret_cast<short8v*>(&sa[1][r * LD + schk * 8]) = vl;
        }
        {
            const short8v vh =
                *reinterpret_cast<const short8v*>(Bh + (size_t)srow * K + kb + schk * 8);
            const short8v vl =
                *reinterpret_cast<const short8v*>(Bl + (size_t)srow * K + kb + schk * 8);
            *reinterpret_cast<short8v*>(&sb[0][srow * LD + schk * 8]) = vh;
            *reinterpret_cast<short8v*>(&sb[1][srow * LD + schk * 8]) = vl;
        }
        __syncthreads();
#pragma unroll
        for (int ks = 0; ks < 2; ks++) {
            const int koff = ks * 16 + (lane >> 5) * 8;
            const int ar = wid * 32 + (lane & 31);
            const short8v ah = *reinterpret_cast<const short8v*>(&sa[0][ar * LD + koff]);
            const short8v al = *reinterpret_cast<const short8v*>(&sa[1][ar * LD + koff]);
            short8v bh[2], bl[2];
#pragma unroll
            for (int n = 0; n < 2; n++) {
                const int br = n * 32 + (lane & 31);
                bh[n] = *reinterpret_cast<const short8v*>(&sb[0][br * LD + koff]);
                bl[n] = *reinterpret_cast<const short8v*>(&sb[1][br * LD + koff]);
            }
#pragma unroll
            for (int n = 0; n < 2; n++) {
                acc[n] = __builtin_amdgcn_mfma_f32_32x32x16_bf16(ah, bh[n], acc[n], 0, 0, 0);
                acc[n] = __builtin_amdgcn_mfma_f32_32x32x16_bf16(ah, bl[n], acc[n], 0, 0, 0);
                acc[n] = __builtin_amdgcn_mfma_f32_32x32x16_bf16(al, bh[n], acc[n], 0, 0, 0);
            }
        }
    }

    const int rowb = n0 + wid * 32 + 4 * (lane >> 5);
#pragma unroll
    for (int n = 0; n < 2; n++) {
        const int c = (lane & 31) + n * 32;
        const float bv = bias[hh * 64 + c];
#pragma unroll
        for (int r = 0; r < 16; r++) {
            const int row = rowb + (r & 3) + 8 * (r >> 2);
            if (row < N) {
                float ov = acc[n][r] + bv;
                ov = (ov > 0.f) ? ov : expm1f(ov);
                const unsigned short hb = f2bf(ov);
                Ohi[(size_t)row * 256 + hh * 64 + c] = hb;
                Olo[(size_t)row * 256 + hh * 64 + c] = f2bf(ov - bf2f(hb));
            }
        }
    }
}

// ----------------------------- z GEMM (layers 1,2) ---------------------------
// Zb[N,COLS] (BF16) = X @ W (bf16x3). Epilogue also emits As/Ad = z . att
// (WN=64: each wave owns one head's 64 cols; 32-lane shfl butterfly).
template <int K, int COLS, int BM, int BN, int WN>
__global__ __launch_bounds__(256) void k_gemm_z(
    const unsigned short* __restrict__ Ahi, const unsigned short* __restrict__ Alo,
    const unsigned short* __restrict__ Bhi, const unsigned short* __restrict__ Blo,
    const float* __restrict__ att_src, const float* __restrict__ att_dst,
    unsigned short* __restrict__ Zb, float* __restrict__ As, float* __restrict__ Ad, int N) {
    constexpr int LD = 40;
    constexpr int WAVES_N = BN / WN;
    constexpr int WAVES_M = 4 / WAVES_N;
    constexpr int WM = BM / WAVES_M;
    constexpr int MW = WM / 32, NW = WN / 32;
    constexpr int H = COLS / 64;
    __shared__ unsigned short sa[2][BM * LD];
    __shared__ unsigned short sb[2][BN * LD];

    const int tid = threadIdx.x;
    const int n0 = blockIdx.x * BM;
    const int c0 = blockIdx.y * BN;
    const int wid = tid >> 6, lane = tid & 63;
    const int wr = wid / WAVES_N, wc = wid % WAVES_N;

    f32x16 acc[MW][NW];
#pragma unroll
    for (int m = 0; m < MW; m++)
#pragma unroll
        for (int n = 0; n < NW; n++)
#pragma unroll
            for (int i = 0; i < 16; i++) acc[m][n][i] = 0.f;

    const int srow = tid >> 2, schk = tid & 3;

    for (int kb = 0; kb < K; kb += 32) {
        __syncthreads();
#pragma unroll
        for (int rr = 0; rr < BM / 64; rr++) {
            const int r = srow + rr * 64;
            const int row = n0 + r;
            short8v vh = {0, 0, 0, 0, 0, 0, 0, 0}, vl = {0, 0, 0, 0, 0, 0, 0, 0};
            if (row < N) {
                vh = *reinterpret_cast<const short8v*>(Ahi + (size_t)row * K + kb + schk * 8);
                vl = *reinterpret_cast<const short8v*>(Alo + (size_t)row * K + kb + schk * 8);
            }
            *reinterpret_cast<short8v*>(&sa[0][r * LD + schk * 8]) = vh;
            *reinterpret_cast<short8v*>(&sa[1][r * LD + schk * 8]) = vl;
        }
#pragma unroll
        for (int rr = 0; rr < BN / 64; rr++) {
            const int cc = srow + rr * 64;
            const short8v vh =
                *reinterpret_cast<const short8v*>(Bhi + (size_t)(c0 + cc) * K + kb + schk * 8);
            const short8v vl =
                *reinterpret_cast<const short8v*>(Blo + (size_t)(c0 + cc) * K + kb + schk * 8);
            *reinterpret_cast<short8v*>(&sb[0][cc * LD + schk * 8]) = vh;
            *reinterpret_cast<short8v*>(&sb[1][cc * LD + schk * 8]) = vl;
        }
        __syncthreads();
#pragma unroll
        for (int ks = 0; ks < 2; ks++) {
            const int koff = ks * 16 + (lane >> 5) * 8;
            short8v ah[MW], al[MW], bh[NW], bl[NW];
#pragma unroll
            for (int m = 0; m < MW; m++) {
                const int ar = wr * WM + m * 32 + (lane & 31);
                ah[m] = *reinterpret_cast<const short8v*>(&sa[0][ar * LD + koff]);
                al[m] = *reinterpret_cast<const short8v*>(&sa[1][ar * LD + koff]);
            }
#pragma unroll
            for (int n = 0; n < NW; n++) {
                const int br = wc * WN + n * 32 + (lane & 31);
                bh[n] = *reinterpret_cast<const short8v*>(&sb[0][br * LD + koff]);
                bl[n] = *reinterpret_cast<const short8v*>(&sb[1][br * LD + koff]);
            }
#pragma unroll
            for (int m = 0; m < MW; m++)
#pragma unroll
                for (int n = 0; n < NW; n++) {
                    acc[m][n] = __builtin_amdgcn_mfma_f32_32x32x16_bf16(ah[m], bh[n], acc[m][n], 0, 0, 0);
                    acc[m][n] = __builtin_amdgcn_mfma_f32_32x32x16_bf16(ah[m], bl[n], acc[m][n], 0, 0, 0);
                    acc[m][n] = __builtin_amdgcn_mfma_f32_32x32x16_bf16(al[m], bh[n], acc[m][n], 0, 0, 0);
                }
        }
    }

    const int colb = c0 + wc * WN + (lane & 31);
    const int rowb = n0 + wr * WM + 4 * (lane >> 5);
#pragma unroll
    for (int m = 0; m < MW; m++)
#pragma unroll
        for (int n = 0; n < NW; n++)
#pragma unroll
            for (int r = 0; r < 16; r++) {
                const int row = rowb + m * 32 + (r & 3) + 8 * (r >> 2);
                if (row < N) Zb[(size_t)row * COLS + colb + n * 32] = f2bf(acc[m][n][r]);
            }

    const int hh = (c0 + wc * WN) >> 6;
    float asv[NW], adv[NW];
#pragma unroll
    for (int n = 0; n < NW; n++) {
        asv[n] = att_src[colb + n * 32];
        adv[n] = att_dst[colb + n * 32];
    }
#pragma unroll
    for (int m = 0; m < MW; m++)
#pragma unroll
        for (int r = 0; r < 16; r++) {
            const int row = rowb + m * 32 + (r & 3) + 8 * (r >> 2);
            float ps = 0.f, pd = 0.f;
#pragma unroll
            for (int n = 0; n < NW; n++) {
                ps = fmaf(acc[m][n][r], asv[n], ps);
                pd = fmaf(acc[m][n][r], adv[n], pd);
            }
#pragma unroll
            for (int off = 1; off < 32; off <<= 1) {
                ps += __shfl_xor(ps, off, 64);
                pd += __shfl_xor(pd, off, 64);
            }
            if ((lane & 31) == 0 && row < N) {
                As[(size_t)row * H + hh] = ps;
                Ad[(size_t)row * H + hh] = pd;
            }
        }
}

// ----------------------------- global max pool helpers -----------------------
__device__ __forceinline__ unsigned fenc(float f) {
    unsigned u = __float_as_uint(f);
    return (u & 0x80000000u) ? ~u : (u | 0x80000000u);
}

// ----------------------------- layer-1 aggregate (all heads) -----------------
// One wave per node. Lane: head h = lane>>4, channels (lane&15)*4..+3. Per edge
// ONE ushort4 load covers this lane's 4 bf16 channels (512B/edge wave-wide,
// all 4 heads). Weights via readlane broadcasts; denominators accumulate
// uniformly (no reduction). Output: normalized+bias+ELU bf16 hi/lo planes.
__global__ __launch_bounds__(256) void k_agg4(
    const unsigned short* __restrict__ Zb, const float* __restrict__ As,
    const float* __restrict__ Ad, const int* __restrict__ rowptr,
    const int* __restrict__ col, const float* __restrict__ bias,
    unsigned short* __restrict__ ohi, unsigned short* __restrict__ olo, int N) {
    const int n = blockIdx.x * 4 + (threadIdx.x >> 6);
    const int lane = threadIdx.x & 63;
    if (n >= N) return;
    const int h = lane >> 4;

    const int start = rowptr[n];
    const int total = rowptr[n + 1] - start;  // includes self-loop
    const int* __restrict__ cp = col + start;
    const float4 adn = *reinterpret_cast<const float4*>(Ad + (size_t)n * 4);
    const unsigned short* __restrict__ Zl = Zb + lane * 4;

    float a0 = 0.f, a1 = 0.f, a2 = 0.f, a3 = 0.f;
    float d0 = 0.f, d1 = 0.f, d2 = 0.f, d3 = 0.f;

    for (int base = 0; base < total; base += 64) {
        const int cnt = min(64, total - base);
        const int i = base + lane;
        int s = 0;
        float4 w = make_float4(0.f, 0.f, 0.f, 0.f);
        if (i < total) {
            s = cp[i];
            const float4 av = *reinterpret_cast<const float4*>(As + (size_t)s * 4);
            w.x = __expf(lrelu(av.x + adn.x));
            w.y = __expf(lrelu(av.y + adn.y));
            w.z = __expf(lrelu(av.z + adn.z));
            w.w = __expf(lrelu(av.w + adn.w));
        }

        int jj = 0;
        for (; jj + 8 <= cnt; jj += 8) {
            int sb[8];
            float w0[8], w1[8], w2[8], w3[8];
            ushort4 zb[8];
#pragma unroll
            for (int u = 0; u < 8; u++) {
                sb[u] = __builtin_amdgcn_readlane(s, jj + u);
                w0[u] = readlane_f(w.x, jj + u);
                w1[u] = readlane_f(w.y, jj + u);
                w2[u] = readlane_f(w.z, jj + u);
                w3[u] = readlane_f(w.w, jj + u);
            }
#pragma unroll
            for (int u = 0; u < 8; u++)
                zb[u] = *reinterpret_cast<const ushort4*>(Zl + (size_t)sb[u] * 256);
#pragma unroll
            for (int u = 0; u < 8; u++) {
                const float ws = (h == 0) ? w0[u] : (h == 1) ? w1[u] : (h == 2) ? w2[u] : w3[u];
                a0 = fmaf(ws, bf2f(zb[u].x), a0);
                a1 = fmaf(ws, bf2f(zb[u].y), a1);
                a2 = fmaf(ws, bf2f(zb[u].z), a2);
                a3 = fmaf(ws, bf2f(zb[u].w), a3);
                d0 += w0[u]; d1 += w1[u]; d2 += w2[u]; d3 += w3[u];
            }
        }
        for (; jj + 4 <= cnt; jj += 4) {
            int sb[4];
            float w0[4], w1[4], w2[4], w3[4];
            ushort4 zb[4];
#pragma unroll
            for (int u = 0; u < 4; u++) {
                sb[u] = __builtin_amdgcn_readlane(s, jj + u);
                w0[u] = readlane_f(w.x, jj + u);
                w1[u] = readlane_f(w.y, jj + u);
                w2[u] = readlane_f(w.z, jj + u);
                w3[u] = readlane_f(w.w, jj + u);
            }
#pragma unroll
            for (int u = 0; u < 4; u++)
                zb[u] = *reinterpret_cast<const ushort4*>(Zl + (size_t)sb[u] * 256);
#pragma unroll
            for (int u = 0; u < 4; u++) {
                const float ws = (h == 0) ? w0[u] : (h == 1) ? w1[u] : (h == 2) ? w2[u] : w3[u];
                a0 = fmaf(ws, bf2f(zb[u].x), a0);
                a1 = fmaf(ws, bf2f(zb[u].y), a1);
                a2 = fmaf(ws, bf2f(zb[u].z), a2);
                a3 = fmaf(ws, bf2f(zb[u].w), a3);
                d0 += w0[u]; d1 += w1[u]; d2 += w2[u]; d3 += w3[u];
            }
        }
        for (; jj < cnt; jj++) {
            const int s0 = __builtin_amdgcn_readlane(s, jj);
            const float e0 = readlane_f(w.x, jj), e1 = readlane_f(w.y, jj);
            const float e2 = readlane_f(w.z, jj), e3 = readlane_f(w.w, jj);
            const ushort4 zb = *reinterpret_cast<const ushort4*>(Zl + (size_t)s0 * 256);
            const float ws = (h == 0) ? e0 : (h == 1) ? e1 : (h == 2) ? e2 : e3;
            a0 = fmaf(ws, bf2f(zb.x), a0);
            a1 = fmaf(ws, bf2f(zb.y), a1);
            a2 = fmaf(ws, bf2f(zb.z), a2);
            a3 = fmaf(ws, bf2f(zb.w), a3);
            d0 += e0; d1 += e1; d2 += e2; d3 += e3;
        }
    }

    const float den = (h == 0) ? d0 : (h == 1) ? d1 : (h == 2) ? d2 : d3;
    const float inv = 1.f / (den + 1e-16f);
    float o[4] = {a0, a1, a2, a3};
    ushort4 vh, vl;
#pragma unroll
    for (int j = 0; j < 4; j++) {
        float ov = o[j] * inv + bias[lane * 4 + j];
        ov = (ov > 0.f) ? ov : expm1f(ov);
        o[j] = ov;
    }
    const unsigned short b0 = f2bf(o[0]), b1 = f2bf(o[1]), b2 = f2bf(o[2]), b3 = f2bf(o[3]);
    vh = make_ushort4(b0, b1, b2, b3);
    vl = make_ushort4(f2bf(o[0] - bf2f(b0)), f2bf(o[1] - bf2f(b1)),
                      f2bf(o[2] - bf2f(b2)), f2bf(o[3] - bf2f(b3)));
    *reinterpret_cast<ushort4*>(ohi + (size_t)n * 256 + lane * 4) = vh;
    *reinterpret_cast<ushort4*>(olo + (size_t)n * 256 + lane * 4) = vl;
}

// ----------------------------- layer-2 aggregate + pool ----------------------
// Wave per node (H=1). Lane = channel; bf16 z gather (128B/edge), uniform
// denom via broadcast weights, fused encoded atomicMax pool.
__global__ __launch_bounds__(256) void k_agg1(
    const unsigned short* __restrict__ Zb, const float* __restrict__ As,
    const float* __restrict__ Ad, const int* __restrict__ rowptr,
    const int* __restrict__ col, const float* __restrict__ bias,
    const int* __restrict__ batch, unsigned* __restrict__ enc, int N) {
    const int n = blockIdx.x * 4 + (threadIdx.x >> 6);
    const int lane = threadIdx.x & 63;
    if (n >= N) return;

    const int start = rowptr[n];
    const int total = rowptr[n + 1] - start;  // includes self-loop
    const int* __restrict__ cp = col + start;
    const float adn = Ad[n];

    float acc = 0.f, denom = 0.f;

    for (int base = 0; base < total; base += 64) {
        const int cnt = min(64, total - base);
        const int i = base + lane;
        int s = 0;
        float w = 0.f;
        if (i < total) {
            s = cp[i];
            w = __expf(lrelu(As[s] + adn));
        }

        int jj = 0;
        for (; jj + 8 <= cnt; jj += 8) {
            int sb[8];
            float wb[8], zb[8];
#pragma unroll
            for (int u = 0; u < 8; u++) {
                sb[u] = __builtin_amdgcn_readlane(s, jj + u);
                wb[u] = readlane_f(w, jj + u);
            }
#pragma unroll
            for (int u = 0; u < 8; u++) zb[u] = bf2f(Zb[(size_t)sb[u] * 64 + lane]);
#pragma unroll
            for (int u = 0; u < 8; u++) {
                acc = fmaf(wb[u], zb[u], acc);
                denom += wb[u];
            }
        }
        for (; jj < cnt; jj++) {
            const int s0 = __builtin_amdgcn_readlane(s, jj);
            const float w0 = readlane_f(w, jj);
            acc = fmaf(w0, bf2f(Zb[(size_t)s0 * 64 + lane]), acc);
            denom += w0;
        }
    }

    const float ov = acc / (denom + 1e-16f) + bias[lane];
    const int g = batch[n];
    atomicMax(&enc[g * 64 + lane], fenc(ov));
}

__global__ void k_decode(const unsigned* __restrict__ enc, float* __restrict__ out, int M) {
    int id = blockIdx.x * 256 + threadIdx.x;
    if (id < M) {
        unsigned e = enc[id];
        unsigned u = (e & 0x80000000u) ? (e & 0x7FFFFFFFu) : ~e;
        out[id] = __uint_as_float(u);
    }
}

// ----------------------------- launch ---------------------------------------
extern "C" void kernel_launch(void* const* d_in, const int* in_sizes, int n_in,
                              void* d_out, int out_size, void* d_ws, size_t ws_size,
                              hipStream_t stream) {
    const float* x = (const float*)d_in[0];
    const int* edge_index = (const int*)d_in[1];
    const int* batch = (const int*)d_in[2];
    const float* W0 = (const float*)d_in[3];
    const float* as0 = (const float*)d_in[4];
    const float* ad0 = (const float*)d_in[5];
    const float* b0 = (const float*)d_in[6];
    const float* W1 = (const float*)d_in[7];
    const float* as1 = (const float*)d_in[8];
    const float* ad1 = (const float*)d_in[9];
    const float* b1 = (const float*)d_in[10];
    const float* W2 = (const float*)d_in[11];
    const float* as2 = (const float*)d_in[12];
    const float* ad2 = (const float*)d_in[13];
    const float* b2 = (const float*)d_in[14];

    const int N = in_sizes[0] / 64;  // nodes
    const int E = in_sizes[1] / 2;   // edges (no self-loops)
    const int G = out_size / 64;     // graphs
    const int Et = E + N;            // edges incl. self-loops

    const int* srcs = edge_index;
    const int* dsts = edge_index + E;

    char* p = (char*)d_ws;
    auto alloc = [&](size_t bytes) {
        void* r = (void*)p;
        p += (bytes + 255) & ~(size_t)255;
        return r;
    };
    unsigned short* Zb = (unsigned short*)alloc((size_t)N * 256 * 2);  // bf16 z
    unsigned short* Hbhi = (unsigned short*)alloc((size_t)N * 256 * 2);
    unsigned short* Hblo = (unsigned short*)alloc((size_t)N * 256 * 2);
    unsigned short* Axhi = (unsigned short*)alloc((size_t)N * 256 * 2);
    unsigned short* Axlo = (unsigned short*)alloc((size_t)N * 256 * 2);
    float* As = (float*)alloc((size_t)N * 4 * 4);
    float* Ad = (float*)alloc((size_t)N * 4 * 4);
    int* deg = (int*)alloc((size_t)N * 4);
    int* incl = (int*)alloc((size_t)N * 4);
    int* bsum = (int*)alloc(1024 * 4);
    int* rowptr = (int*)alloc((size_t)(N + 1) * 4);
    int* cursor = (int*)alloc((size_t)N * 4);
    int* col = (int*)alloc((size_t)Et * 4);
    unsigned short* wt0h = (unsigned short*)alloc(256 * 64 * 2);
    unsigned short* wt0l = (unsigned short*)alloc(256 * 64 * 2);
    unsigned short* wt1h = (unsigned short*)alloc(256 * 256 * 2);
    unsigned short* wt1l = (unsigned short*)alloc(256 * 256 * 2);
    unsigned short* wt2h = (unsigned short*)alloc(64 * 256 * 2);
    unsigned short* wt2l = (unsigned short*)alloc(64 * 256 * 2);
    float* vs0 = (float*)alloc(4 * 64 * 4);
    float* vd0 = (float*)alloc(4 * 64 * 4);
    unsigned* enc = (unsigned*)alloc((size_t)G * 64 * 4);

    hipMemsetAsync(deg, 0, (size_t)N * 4, stream);
    hipMemsetAsync(enc, 0, (size_t)G * 64 * 4, stream);

    const int eb = (E + 255) / 256;
    const int nb = (N + 255) / 256;  // scan blocks (<=1024 nodes*256)
    const int ab = (N + 3) / 4;
    const int gm = (N + 127) / 128;

    k_count<<<eb, 256, 0, stream>>>(dsts, E, deg);
    k_scan1<<<nb, 256, 0, stream>>>(deg, incl, bsum, N);
    k_scan2<<<1, 1024, 0, stream>>>(bsum, nb);
    k_scan3<<<nb, 256, 0, stream>>>(deg, incl, bsum, rowptr, cursor, N, nb);
    k_scatter<<<(Et + 255) / 256, 256, 0, stream>>>(srcs, dsts, E, N, cursor, col);

    k_wconv<64, 256><<<(64 * 256 + 255) / 256, 256, 0, stream>>>(W0, wt0h, wt0l);
    k_wconv<256, 256><<<(256 * 256 + 255) / 256, 256, 0, stream>>>(W1, wt1h, wt1l);
    k_wconv<256, 64><<<(256 * 64 + 255) / 256, 256, 0, stream>>>(W2, wt2h, wt2l);
    k_attvec<<<1, 64, 0, stream>>>(W0, as0, ad0, vs0, vd0);

    // Layer 0: As0/Ad0 from x; aggregate x; project+bias+ELU (post-GEMM)
    k_att0<<<ab, 256, 0, stream>>>(x, vs0, vd0, As, Ad, N);
    k_aggx<<<ab, 256, 0, stream>>>(x, As, Ad, rowptr, col, Axhi, Axlo, N);
    k_gemm_pe<<<dim3(gm, 4), 256, 0, stream>>>(Axhi, Axlo, wt0h, wt0l, b0, Hbhi, Hblo, N);

    // Layer 1: z GEMM (bf16 out, fused As/Ad) + all-heads aggregate
    k_gemm_z<256, 256, 128, 128, 64><<<dim3(gm, 2), 256, 0, stream>>>(
        Hbhi, Hblo, wt1h, wt1l, as1, ad1, Zb, As, Ad, N);
    k_agg4<<<ab, 256, 0, stream>>>(Zb, As, Ad, rowptr, col, b1, Hbhi, Hblo, N);

    // Layer 2: z GEMM (bf16 out, fused As/Ad) + aggregate + fused pool
    k_gemm_z<256, 64, 128, 64, 64><<<dim3(gm, 1), 256, 0, stream>>>(
        Hbhi, Hblo, wt2h, wt2l, as2, ad2, Zb, As, Ad, N);
    k_agg1<<<ab, 256, 0, stream>>>(Zb, As, Ad, rowptr, col, b2, batch, enc, N);
    k_decode<<<(G * 64 + 255) / 256, 256, 0, stream>>>(enc, (float*)d_out, G * 64);
}

// Round 11
// 390.799 us; speedup vs baseline: 1.7900x; 1.0269x over previous
//
#include <hip/hip_runtime.h>
#include <math.h>

// ---------------------------------------------------------------------------
// GAT encoder: 3 GATConv layers (H=4,4,1) + ELU + global max pool.
// Layer 0: aggregate-then-project (x-row gather serves all 4 heads) + fused
//   post-GEMM (aggx @ W0 + b0, ELU) on matrix cores (bf16x3).
// Layers 1/2: project-then-aggregate; z stored BF16 (XCD-redundant gather
//   floor = 8 x Zb = 209 MB, measured). Aggregates use an LDS weight
//   transpose: preamble ds_write_b128 of each edge's 4 head-weights, gather
//   loop does ONE broadcast ds_read per edge instead of 4 readlanes + selects.
// CSR build: hierarchical 3-pass parallel scan. Setup (W splits + att
//   vectors) merged into one kernel.
// bf16x3 GEMM: fp32 ~ hi+lo bf16; hi*hi+hi*lo+lo*hi MFMA, rel err ~2^-17.
// ---------------------------------------------------------------------------

typedef __attribute__((ext_vector_type(8))) short short8v;
typedef __attribute__((ext_vector_type(16))) float f32x16;

__device__ __forceinline__ float lrelu(float x) { return x > 0.f ? x : 0.2f * x; }

__device__ __forceinline__ unsigned short f2bf(float x) {  // RNE
    unsigned u = __float_as_uint(x);
    return (unsigned short)((u + 0x7FFFu + ((u >> 16) & 1u)) >> 16);
}
__device__ __forceinline__ float bf2f(unsigned short h) {
    return __uint_as_float(((unsigned)h) << 16);
}
__device__ __forceinline__ float readlane_f(float v, int l) {
    return __uint_as_float((unsigned)__builtin_amdgcn_readlane((int)__float_as_uint(v), l));
}

// ----------------------------- CSR build -----------------------------------
__global__ void k_count(const int* __restrict__ dst, int E, int* __restrict__ deg) {
    int e = blockIdx.x * 256 + threadIdx.x;
    if (e < E) atomicAdd(&deg[dst[e]], 1);
}

// Pass 1: per-block inclusive scan of (deg[i]+1); write local prefix + block sum
__global__ __launch_bounds__(256) void k_scan1(const int* __restrict__ deg,
                                               int* __restrict__ incl,
                                               int* __restrict__ bsum, int N) {
    const int i = blockIdx.x * 256 + threadIdx.x;
    const int lane = threadIdx.x & 63;
    const int wv = threadIdx.x >> 6;
    int sc = (i < N) ? deg[i] + 1 : 0;
#pragma unroll
    for (int off = 1; off < 64; off <<= 1) {
        int t = __shfl_up(sc, off, 64);
        if (lane >= off) sc += t;
    }
    __shared__ int wsum[4];
    if (lane == 63) wsum[wv] = sc;
    __syncthreads();
    int woff = 0;
#pragma unroll
    for (int k = 0; k < 3; k++)
        if (wv > k) woff += wsum[k];
    sc += woff;
    if (i < N) incl[i] = sc;
    if (threadIdx.x == 255) bsum[blockIdx.x] = sc;
}

// Pass 2: single block inclusive scan of block sums (nb <= 1024)
__global__ __launch_bounds__(1024) void k_scan2(int* __restrict__ bsum, int nb) {
    const int t = threadIdx.x;
    const int lane = t & 63;
    const int wv = t >> 6;
    int sc = (t < nb) ? bsum[t] : 0;
#pragma unroll
    for (int off = 1; off < 64; off <<= 1) {
        int u = __shfl_up(sc, off, 64);
        if (lane >= off) sc += u;
    }
    __shared__ int wsum[16];
    if (lane == 63) wsum[wv] = sc;
    __syncthreads();
    int woff = 0;
#pragma unroll
    for (int k = 0; k < 15; k++)
        if (wv > k) woff += wsum[k];
    sc += woff;
    if (t < nb) bsum[t] = sc;
}

// Pass 3: exclusive global offsets -> rowptr/cursor; rowptr[N] = total
__global__ void k_scan3(const int* __restrict__ deg, const int* __restrict__ incl,
                        const int* __restrict__ bsum, int* __restrict__ rowptr,
                        int* __restrict__ cursor, int N, int nb) {
    int i = blockIdx.x * 256 + threadIdx.x;
    if (i < N) {
        const int off = (blockIdx.x > 0) ? bsum[blockIdx.x - 1] : 0;
        const int excl = incl[i] + off - (deg[i] + 1);
        rowptr[i] = excl;
        cursor[i] = excl;
        if (i == N - 1) rowptr[N] = bsum[nb - 1];
    }
}

// edges AND self-loops in one pass
__global__ void k_scatter(const int* __restrict__ src, const int* __restrict__ dst, int E,
                          int N, int* __restrict__ cursor, int* __restrict__ col) {
    int e = blockIdx.x * 256 + threadIdx.x;
    if (e < E) {
        int d = dst[e];
        int p = atomicAdd(&cursor[d], 1);
        col[p] = src[e];
    } else if (e < E + N) {
        int n = e - E;
        int p = atomicAdd(&cursor[n], 1);
        col[p] = n;
    }
}

// ----------------------------- fused setup -----------------------------------
// Blocks [0,64): W0 split; [64,320): W1 split; [320,384): W2 split;
// block 384: vs0/vd0 = W0 @ att_src0 / att_dst0.
__global__ void k_setup(const float* __restrict__ W0, const float* __restrict__ W1,
                        const float* __restrict__ W2, const float* __restrict__ as0,
                        const float* __restrict__ ad0,
                        unsigned short* __restrict__ wt0h, unsigned short* __restrict__ wt0l,
                        unsigned short* __restrict__ wt1h, unsigned short* __restrict__ wt1l,
                        unsigned short* __restrict__ wt2h, unsigned short* __restrict__ wt2l,
                        float* __restrict__ vs0, float* __restrict__ vd0) {
    const int b = blockIdx.x;
    const int t = threadIdx.x;
    if (b < 64) {  // wt0: [256][64] from W0[64][256]
        const int i = b * 256 + t;
        const int c = i / 64, k = i % 64;
        const float xw = W0[(size_t)k * 256 + c];
        const unsigned short h = f2bf(xw);
        wt0h[i] = h;
        wt0l[i] = f2bf(xw - bf2f(h));
    } else if (b < 320) {  // wt1: [256][256] from W1[256][256]
        const int i = (b - 64) * 256 + t;
        const int c = i / 256, k = i % 256;
        const float xw = W1[(size_t)k * 256 + c];
        const unsigned short h = f2bf(xw);
        wt1h[i] = h;
        wt1l[i] = f2bf(xw - bf2f(h));
    } else if (b < 384) {  // wt2: [64][256] from W2[256][64]
        const int i = (b - 320) * 256 + t;
        const int c = i / 256, k = i % 256;
        const float xw = W2[(size_t)k * 64 + c];
        const unsigned short h = f2bf(xw);
        wt2h[i] = h;
        wt2l[i] = f2bf(xw - bf2f(h));
    } else {  // att vectors for layer 0
        const int k = t;
        if (k < 64) {
            for (int h = 0; h < 4; h++) {
                float s = 0.f, d = 0.f;
                for (int c = 0; c < 64; c++) {
                    float w = W0[(size_t)k * 256 + h * 64 + c];
                    s = fmaf(w, as0[h * 64 + c], s);
                    d = fmaf(w, ad0[h * 64 + c], d);
                }
                vs0[h * 64 + k] = s;
                vd0[h * 64 + k] = d;
            }
        }
    }
}

// As0[n,h] = x[n,:] . vs0[h,:]  (wave per node)
__global__ __launch_bounds__(256) void k_att0(
    const float* __restrict__ X, const float* __restrict__ vs, const float* __restrict__ vd,
    float* __restrict__ As, float* __restrict__ Ad, int N) {
    const int n = blockIdx.x * 4 + (threadIdx.x >> 6);
    const int lane = threadIdx.x & 63;
    if (n >= N) return;
    const float xv = X[(size_t)n * 64 + lane];
#pragma unroll
    for (int h = 0; h < 4; h++) {
        float ps = xv * vs[h * 64 + lane];
        float pd = xv * vd[h * 64 + lane];
#pragma unroll
        for (int off = 1; off < 64; off <<= 1) {
            ps += __shfl_xor(ps, off, 64);
            pd += __shfl_xor(pd, off, 64);
        }
        if (lane == 0) {
            As[(size_t)n * 4 + h] = ps;
            Ad[(size_t)n * 4 + h] = pd;
        }
    }
}

// ----------------------------- layer-0 x-aggregate ---------------------------
// Wave per node, lane = x-dim. One 256B x-row gather per edge serves all 4
// heads. Weights via LDS transpose: 1 ds_read_b128 per edge (was 4 readlanes).
__global__ __launch_bounds__(256) void k_aggx(
    const float* __restrict__ X, const float* __restrict__ As, const float* __restrict__ Ad,
    const int* __restrict__ rowptr, const int* __restrict__ col,
    unsigned short* __restrict__ ohi, unsigned short* __restrict__ olo, int N) {
    __shared__ float wlds[4][64][4];
    const int wv = threadIdx.x >> 6;
    const int n = blockIdx.x * 4 + wv;
    const int lane = threadIdx.x & 63;
    if (n >= N) return;

    const int start = rowptr[n];
    const int total = rowptr[n + 1] - start;  // includes self-loop
    const int* __restrict__ cp = col + start;
    const float4 adn = *reinterpret_cast<const float4*>(Ad + (size_t)n * 4);

    float a0 = 0.f, a1 = 0.f, a2 = 0.f, a3 = 0.f;
    float d0 = 0.f, d1 = 0.f, d2 = 0.f, d3 = 0.f;

    for (int base = 0; base < total; base += 64) {
        const int cnt = min(64, total - base);
        const int i = base + lane;
        int s = 0;
        float4 w = make_float4(0.f, 0.f, 0.f, 0.f);
        if (i < total) {
            s = cp[i];
            const float4 av = *reinterpret_cast<const float4*>(As + (size_t)s * 4);
            w.x = __expf(lrelu(av.x + adn.x));
            w.y = __expf(lrelu(av.y + adn.y));
            w.z = __expf(lrelu(av.z + adn.z));
            w.w = __expf(lrelu(av.w + adn.w));
        }
        *reinterpret_cast<float4*>(&wlds[wv][lane][0]) = w;

        int jj = 0;
        for (; jj + 4 <= cnt; jj += 4) {
            int sb[4];
            float4 wj[4];
            float xv[4];
#pragma unroll
            for (int u = 0; u < 4; u++) {
                sb[u] = __builtin_amdgcn_readlane(s, jj + u);
                wj[u] = *reinterpret_cast<const float4*>(&wlds[wv][jj + u][0]);
            }
#pragma unroll
            for (int u = 0; u < 4; u++) xv[u] = X[(size_t)sb[u] * 64 + lane];
#pragma unroll
            for (int u = 0; u < 4; u++) {
                a0 = fmaf(wj[u].x, xv[u], a0);
                a1 = fmaf(wj[u].y, xv[u], a1);
                a2 = fmaf(wj[u].z, xv[u], a2);
                a3 = fmaf(wj[u].w, xv[u], a3);
                d0 += wj[u].x; d1 += wj[u].y; d2 += wj[u].z; d3 += wj[u].w;
            }
        }
        for (; jj < cnt; jj++) {
            const int s0 = __builtin_amdgcn_readlane(s, jj);
            const float4 wj = *reinterpret_cast<const float4*>(&wlds[wv][jj][0]);
            const float xv = X[(size_t)s0 * 64 + lane];
            a0 = fmaf(wj.x, xv, a0);
            a1 = fmaf(wj.y, xv, a1);
            a2 = fmaf(wj.z, xv, a2);
            a3 = fmaf(wj.w, xv, a3);
            d0 += wj.x; d1 += wj.y; d2 += wj.z; d3 += wj.w;
        }
    }

    const float o[4] = {a0 / (d0 + 1e-16f), a1 / (d1 + 1e-16f),
                        a2 / (d2 + 1e-16f), a3 / (d3 + 1e-16f)};
#pragma unroll
    for (int h = 0; h < 4; h++) {
        const unsigned short hb = f2bf(o[h]);
        ohi[(size_t)n * 256 + h * 64 + lane] = hb;
        olo[(size_t)n * 256 + h * 64 + lane] = f2bf(o[h] - bf2f(hb));
    }
}

// ----------------------------- post-GEMM (layer 0) ---------------------------
// Hb[n, h*64+c] = ELU(aggx[n, h*64+:64] @ W0[:, h*64+c] + b0[h*64+c]).
__global__ __launch_bounds__(256) void k_gemm_pe(
    const unsigned short* __restrict__ Ahi, const unsigned short* __restrict__ Alo,
    const unsigned short* __restrict__ Bhi, const unsigned short* __restrict__ Blo,
    const float* __restrict__ bias, unsigned short* __restrict__ Ohi,
    unsigned short* __restrict__ Olo, int N) {
    constexpr int LD = 40, BM = 128, K = 64;
    __shared__ unsigned short sa[2][BM * LD];
    __shared__ unsigned short sb[2][64 * LD];

    const int tid = threadIdx.x;
    const int n0 = blockIdx.x * BM;
    const int hh = blockIdx.y;
    const int wid = tid >> 6, lane = tid & 63;

    const unsigned short* __restrict__ Ah = Ahi + hh * 64;
    const unsigned short* __restrict__ Al = Alo + hh * 64;
    const unsigned short* __restrict__ Bh = Bhi + hh * 64 * K;
    const unsigned short* __restrict__ Bl = Blo + hh * 64 * K;

    f32x16 acc[2];
#pragma unroll
    for (int n = 0; n < 2; n++)
#pragma unroll
        for (int i = 0; i < 16; i++) acc[n][i] = 0.f;

    const int srow = tid >> 2, schk = tid & 3;

    for (int kb = 0; kb < K; kb += 32) {
        __syncthreads();
#pragma unroll
        for (int rr = 0; rr < 2; rr++) {
            const int r = srow + rr * 64;
            const int row = n0 + r;
            short8v vh = {0, 0, 0, 0, 0, 0, 0, 0}, vl = {0, 0, 0, 0, 0, 0, 0, 0};
            if (row < N) {
                vh = *reinterpret_cast<const short8v*>(Ah + (size_t)row * 256 + kb + schk * 8);
                vl = *reinterpret_cast<const short8v*>(Al + (size_t)row * 256 + kb + schk * 8);
            }
            *reinterpret_cast<short8v*>(&sa[0][r * LD + schk * 8]) = vh;
            *reinterpret_cast<short8v*>(&sa[1][r * LD + schk * 8]) = vl;
        }
        {
            const short8v vh =
                *reinterpret_cast<const short8v*>(Bh + (size_t)srow * K + kb + schk * 8);
            const short8v vl =
                *reinterpret_cast<const short8v*>(Bl + (size_t)srow * K + kb + schk * 8);
            *reinterpret_cast<short8v*>(&sb[0][srow * LD + schk * 8]) = vh;
            *reinterpret_cast<short8v*>(&sb[1][srow * LD + schk * 8]) = vl;
        }
        __syncthreads();
#pragma unroll
        for (int ks = 0; ks < 2; ks++) {
            const int koff = ks * 16 + (lane >> 5) * 8;
            const int ar = wid * 32 + (lane & 31);
            const short8v ah = *reinterpret_cast<const short8v*>(&sa[0][ar * LD + koff]);
            const short8v al = *reinterpret_cast<const short8v*>(&sa[1][ar * LD + koff]);
            short8v bh[2], bl[2];
#pragma unroll
            for (int n = 0; n < 2; n++) {
                const int br = n * 32 + (lane & 31);
                bh[n] = *reinterpret_cast<const short8v*>(&sb[0][br * LD + koff]);
                bl[n] = *reinterpret_cast<const short8v*>(&sb[1][br * LD + koff]);
            }
#pragma unroll
            for (int n = 0; n < 2; n++) {
                acc[n] = __builtin_amdgcn_mfma_f32_32x32x16_bf16(ah, bh[n], acc[n], 0, 0, 0);
                acc[n] = __builtin_amdgcn_mfma_f32_32x32x16_bf16(ah, bl[n], acc[n], 0, 0, 0);
                acc[n] = __builtin_amdgcn_mfma_f32_32x32x16_bf16(al, bh[n], acc[n], 0, 0, 0);
            }
        }
    }

    const int rowb = n0 + wid * 32 + 4 * (lane >> 5);
#pragma unroll
    for (int n = 0; n < 2; n++) {
        const int c = (lane & 31) + n * 32;
        const float bv = bias[hh * 64 + c];
#pragma unroll
        for (int r = 0; r < 16; r++) {
            const int row = rowb + (r & 3) + 8 * (r >> 2);
            if (row < N) {
                float ov = acc[n][r] + bv;
                ov = (ov > 0.f) ? ov : expm1f(ov);
                const unsigned short hb = f2bf(ov);
                Ohi[(size_t)row * 256 + hh * 64 + c] = hb;
                Olo[(size_t)row * 256 + hh * 64 + c] = f2bf(ov - bf2f(hb));
            }
        }
    }
}

// ----------------------------- z GEMM (layers 1,2) ---------------------------
// Zb[N,COLS] (BF16) = X @ W (bf16x3). Epilogue also emits As/Ad = z . att
// (WN=64: each wave owns one head's 64 cols; 32-lane shfl butterfly).
template <int K, int COLS, int BM, int BN, int WN>
__global__ __launch_bounds__(256) void k_gemm_z(
    const unsigned short* __restrict__ Ahi, const unsigned short* __restrict__ Alo,
    const unsigned short* __restrict__ Bhi, const unsigned short* __restrict__ Blo,
    const float* __restrict__ att_src, const float* __restrict__ att_dst,
    unsigned short* __restrict__ Zb, float* __restrict__ As, float* __restrict__ Ad, int N) {
    constexpr int LD = 40;
    constexpr int WAVES_N = BN / WN;
    constexpr int WAVES_M = 4 / WAVES_N;
    constexpr int WM = BM / WAVES_M;
    constexpr int MW = WM / 32, NW = WN / 32;
    constexpr int H = COLS / 64;
    __shared__ unsigned short sa[2][BM * LD];
    __shared__ unsigned short sb[2][BN * LD];

    const int tid = threadIdx.x;
    const int n0 = blockIdx.x * BM;
    const int c0 = blockIdx.y * BN;
    const int wid = tid >> 6, lane = tid & 63;
    const int wr = wid / WAVES_N, wc = wid % WAVES_N;

    f32x16 acc[MW][NW];
#pragma unroll
    for (int m = 0; m < MW; m++)
#pragma unroll
        for (int n = 0; n < NW; n++)
#pragma unroll
            for (int i = 0; i < 16; i++) acc[m][n][i] = 0.f;

    const int srow = tid >> 2, schk = tid & 3;

    for (int kb = 0; kb < K; kb += 32) {
        __syncthreads();
#pragma unroll
        for (int rr = 0; rr < BM / 64; rr++) {
            const int r = srow + rr * 64;
            const int row = n0 + r;
            short8v vh = {0, 0, 0, 0, 0, 0, 0, 0}, vl = {0, 0, 0, 0, 0, 0, 0, 0};
            if (row < N) {
                vh = *reinterpret_cast<const short8v*>(Ahi + (size_t)row * K + kb + schk * 8);
                vl = *reinterpret_cast<const short8v*>(Alo + (size_t)row * K + kb + schk * 8);
            }
            *reinterpret_cast<short8v*>(&sa[0][r * LD + schk * 8]) = vh;
            *reinterpret_cast<short8v*>(&sa[1][r * LD + schk * 8]) = vl;
        }
#pragma unroll
        for (int rr = 0; rr < BN / 64; rr++) {
            const int cc = srow + rr * 64;
            const short8v vh =
                *reinterpret_cast<const short8v*>(Bhi + (size_t)(c0 + cc) * K + kb + schk * 8);
            const short8v vl =
                *reinterpret_cast<const short8v*>(Blo + (size_t)(c0 + cc) * K + kb + schk * 8);
            *reinterpret_cast<short8v*>(&sb[0][cc * LD + schk * 8]) = vh;
            *reinterpret_cast<short8v*>(&sb[1][cc * LD + schk * 8]) = vl;
        }
        __syncthreads();
#pragma unroll
        for (int ks = 0; ks < 2; ks++) {
            const int koff = ks * 16 + (lane >> 5) * 8;
            short8v ah[MW], al[MW], bh[NW], bl[NW];
#pragma unroll
            for (int m = 0; m < MW; m++) {
                const int ar = wr * WM + m * 32 + (lane & 31);
                ah[m] = *reinterpret_cast<const short8v*>(&sa[0][ar * LD + koff]);
                al[m] = *reinterpret_cast<const short8v*>(&sa[1][ar * LD + koff]);
            }
#pragma unroll
            for (int n = 0; n < NW; n++) {
                const int br = wc * WN + n * 32 + (lane & 31);
                bh[n] = *reinterpret_cast<const short8v*>(&sb[0][br * LD + koff]);
                bl[n] = *reinterpret_cast<const short8v*>(&sb[1][br * LD + koff]);
            }
#pragma unroll
            for (int m = 0; m < MW; m++)
#pragma unroll
                for (int n = 0; n < NW; n++) {
                    acc[m][n] = __builtin_amdgcn_mfma_f32_32x32x16_bf16(ah[m], bh[n], acc[m][n], 0, 0, 0);
                    acc[m][n] = __builtin_amdgcn_mfma_f32_32x32x16_bf16(ah[m], bl[n], acc[m][n], 0, 0, 0);
                    acc[m][n] = __builtin_amdgcn_mfma_f32_32x32x16_bf16(al[m], bh[n], acc[m][n], 0, 0, 0);
                }
        }
    }

    const int colb = c0 + wc * WN + (lane & 31);
    const int rowb = n0 + wr * WM + 4 * (lane >> 5);
#pragma unroll
    for (int m = 0; m < MW; m++)
#pragma unroll
        for (int n = 0; n < NW; n++)
#pragma unroll
            for (int r = 0; r < 16; r++) {
                const int row = rowb + m * 32 + (r & 3) + 8 * (r >> 2);
                if (row < N) Zb[(size_t)row * COLS + colb + n * 32] = f2bf(acc[m][n][r]);
            }

    const int hh = (c0 + wc * WN) >> 6;
    float asv[NW], adv[NW];
#pragma unroll
    for (int n = 0; n < NW; n++) {
        asv[n] = att_src[colb + n * 32];
        adv[n] = att_dst[colb + n * 32];
    }
#pragma unroll
    for (int m = 0; m < MW; m++)
#pragma unroll
        for (int r = 0; r < 16; r++) {
            const int row = rowb + m * 32 + (r & 3) + 8 * (r >> 2);
            float ps = 0.f, pd = 0.f;
#pragma unroll
            for (int n = 0; n < NW; n++) {
                ps = fmaf(acc[m][n][r], asv[n], ps);
                pd = fmaf(acc[m][n][r], adv[n], pd);
            }
#pragma unroll
            for (int off = 1; off < 32; off <<= 1) {
                ps += __shfl_xor(ps, off, 64);
                pd += __shfl_xor(pd, off, 64);
            }
            if ((lane & 31) == 0 && row < N) {
                As[(size_t)row * H + hh] = ps;
                Ad[(size_t)row * H + hh] = pd;
            }
        }
}

// ----------------------------- global max pool helpers -----------------------
__device__ __forceinline__ unsigned fenc(float f) {
    unsigned u = __float_as_uint(f);
    return (u & 0x80000000u) ? ~u : (u | 0x80000000u);
}

// ----------------------------- layer-1 aggregate (all heads) -----------------
// One wave per node. Lane: head h = lane>>4, channels (lane&15)*4..+3. Per edge
// ONE ushort4 load (512B/edge wave-wide). Weights via LDS transpose: preamble
// ds_write_b128, gather loop does ONE broadcast ds_read of the lane's own head
// weight; denominator = 1 uniform add/edge (no reduction needed).
__global__ __launch_bounds__(256) void k_agg4(
    const unsigned short* __restrict__ Zb, const float* __restrict__ As,
    const float* __restrict__ Ad, const int* __restrict__ rowptr,
    const int* __restrict__ col, const float* __restrict__ bias,
    unsigned short* __restrict__ ohi, unsigned short* __restrict__ olo, int N) {
    __shared__ float wlds[4][64][4];
    const int wv = threadIdx.x >> 6;
    const int n = blockIdx.x * 4 + wv;
    const int lane = threadIdx.x & 63;
    if (n >= N) return;
    const int h = lane >> 4;

    const int start = rowptr[n];
    const int total = rowptr[n + 1] - start;  // includes self-loop
    const int* __restrict__ cp = col + start;
    const float4 adn = *reinterpret_cast<const float4*>(Ad + (size_t)n * 4);
    const unsigned short* __restrict__ Zl = Zb + lane * 4;

    float a0 = 0.f, a1 = 0.f, a2 = 0.f, a3 = 0.f;
    float den = 0.f;

    for (int base = 0; base < total; base += 64) {
        const int cnt = min(64, total - base);
        const int i = base + lane;
        int s = 0;
        float4 w = make_float4(0.f, 0.f, 0.f, 0.f);
        if (i < total) {
            s = cp[i];
            const float4 av = *reinterpret_cast<const float4*>(As + (size_t)s * 4);
            w.x = __expf(lrelu(av.x + adn.x));
            w.y = __expf(lrelu(av.y + adn.y));
            w.z = __expf(lrelu(av.z + adn.z));
            w.w = __expf(lrelu(av.w + adn.w));
        }
        *reinterpret_cast<float4*>(&wlds[wv][lane][0]) = w;

        int jj = 0;
        for (; jj + 8 <= cnt; jj += 8) {
            int sb[8];
            float ws[8];
            ushort4 zb[8];
#pragma unroll
            for (int u = 0; u < 8; u++) {
                sb[u] = __builtin_amdgcn_readlane(s, jj + u);
                ws[u] = wlds[wv][jj + u][h];
            }
#pragma unroll
            for (int u = 0; u < 8; u++)
                zb[u] = *reinterpret_cast<const ushort4*>(Zl + (size_t)sb[u] * 256);
#pragma unroll
            for (int u = 0; u < 8; u++) {
                a0 = fmaf(ws[u], bf2f(zb[u].x), a0);
                a1 = fmaf(ws[u], bf2f(zb[u].y), a1);
                a2 = fmaf(ws[u], bf2f(zb[u].z), a2);
                a3 = fmaf(ws[u], bf2f(zb[u].w), a3);
                den += ws[u];
            }
        }
        for (; jj + 4 <= cnt; jj += 4) {
            int sb[4];
            float ws[4];
            ushort4 zb[4];
#pragma unroll
            for (int u = 0; u < 4; u++) {
                sb[u] = __builtin_amdgcn_readlane(s, jj + u);
                ws[u] = wlds[wv][jj + u][h];
            }
#pragma unroll
            for (int u = 0; u < 4; u++)
                zb[u] = *reinterpret_cast<const ushort4*>(Zl + (size_t)sb[u] * 256);
#pragma unroll
            for (int u = 0; u < 4; u++) {
                a0 = fmaf(ws[u], bf2f(zb[u].x), a0);
                a1 = fmaf(ws[u], bf2f(zb[u].y), a1);
                a2 = fmaf(ws[u], bf2f(zb[u].z), a2);
                a3 = fmaf(ws[u], bf2f(zb[u].w), a3);
                den += ws[u];
            }
        }
        for (; jj < cnt; jj++) {
            const int s0 = __builtin_amdgcn_readlane(s, jj);
            const float ws = wlds[wv][jj][h];
            const ushort4 zb = *reinterpret_cast<const ushort4*>(Zl + (size_t)s0 * 256);
            a0 = fmaf(ws, bf2f(zb.x), a0);
            a1 = fmaf(ws, bf2f(zb.y), a1);
            a2 = fmaf(ws, bf2f(zb.z), a2);
            a3 = fmaf(ws, bf2f(zb.w), a3);
            den += ws;
        }
    }

    const float inv = 1.f / (den + 1e-16f);
    float o[4] = {a0, a1, a2, a3};
#pragma unroll
    for (int j = 0; j < 4; j++) {
        float ov = o[j] * inv + bias[lane * 4 + j];
        ov = (ov > 0.f) ? ov : expm1f(ov);
        o[j] = ov;
    }
    const unsigned short b0 = f2bf(o[0]), b1 = f2bf(o[1]), b2 = f2bf(o[2]), b3 = f2bf(o[3]);
    const ushort4 vh = make_ushort4(b0, b1, b2, b3);
    const ushort4 vl = make_ushort4(f2bf(o[0] - bf2f(b0)), f2bf(o[1] - bf2f(b1)),
                                    f2bf(o[2] - bf2f(b2)), f2bf(o[3] - bf2f(b3)));
    *reinterpret_cast<ushort4*>(ohi + (size_t)n * 256 + lane * 4) = vh;
    *reinterpret_cast<ushort4*>(olo + (size_t)n * 256 + lane * 4) = vl;
}

// ----------------------------- layer-2 aggregate + pool ----------------------
// Wave per node (H=1). Lane = channel; bf16 z gather (128B/edge), broadcast
// weights, fused encoded atomicMax pool.
__global__ __launch_bounds__(256) void k_agg1(
    const unsigned short* __restrict__ Zb, const float* __restrict__ As,
    const float* __restrict__ Ad, const int* __restrict__ rowptr,
    const int* __restrict__ col, const float* __restrict__ bias,
    const int* __restrict__ batch, unsigned* __restrict__ enc, int N) {
    const int n = blockIdx.x * 4 + (threadIdx.x >> 6);
    const int lane = threadIdx.x & 63;
    if (n >= N) return;

    const int start = rowptr[n];
    const int total = rowptr[n + 1] - start;  // includes self-loop
    const int* __restrict__ cp = col + start;
    const float adn = Ad[n];

    float acc = 0.f, denom = 0.f;

    for (int base = 0; base < total; base += 64) {
        const int cnt = min(64, total - base);
        const int i = base + lane;
        int s = 0;
        float w = 0.f;
        if (i < total) {
            s = cp[i];
            w = __expf(lrelu(As[s] + adn));
        }

        int jj = 0;
        for (; jj + 8 <= cnt; jj += 8) {
            int sb[8];
            float wb[8], zb[8];
#pragma unroll
            for (int u = 0; u < 8; u++) {
                sb[u] = __builtin_amdgcn_readlane(s, jj + u);
                wb[u] = readlane_f(w, jj + u);
            }
#pragma unroll
            for (int u = 0; u < 8; u++) zb[u] = bf2f(Zb[(size_t)sb[u] * 64 + lane]);
#pragma unroll
            for (int u = 0; u < 8; u++) {
                acc = fmaf(wb[u], zb[u], acc);
                denom += wb[u];
            }
        }
        for (; jj < cnt; jj++) {
            const int s0 = __builtin_amdgcn_readlane(s, jj);
            const float w0 = readlane_f(w, jj);
            acc = fmaf(w0, bf2f(Zb[(size_t)s0 * 64 + lane]), acc);
            denom += w0;
        }
    }

    const float ov = acc / (denom + 1e-16f) + bias[lane];
    const int g = batch[n];
    atomicMax(&enc[g * 64 + lane], fenc(ov));
}

__global__ void k_decode(const unsigned* __restrict__ enc, float* __restrict__ out, int M) {
    int id = blockIdx.x * 256 + threadIdx.x;
    if (id < M) {
        unsigned e = enc[id];
        unsigned u = (e & 0x80000000u) ? (e & 0x7FFFFFFFu) : ~e;
        out[id] = __uint_as_float(u);
    }
}

// ----------------------------- launch ---------------------------------------
extern "C" void kernel_launch(void* const* d_in, const int* in_sizes, int n_in,
                              void* d_out, int out_size, void* d_ws, size_t ws_size,
                              hipStream_t stream) {
    const float* x = (const float*)d_in[0];
    const int* edge_index = (const int*)d_in[1];
    const int* batch = (const int*)d_in[2];
    const float* W0 = (const float*)d_in[3];
    const float* as0 = (const float*)d_in[4];
    const float* ad0 = (const float*)d_in[5];
    const float* b0 = (const float*)d_in[6];
    const float* W1 = (const float*)d_in[7];
    const float* as1 = (const float*)d_in[8];
    const float* ad1 = (const float*)d_in[9];
    const float* b1 = (const float*)d_in[10];
    const float* W2 = (const float*)d_in[11];
    const float* as2 = (const float*)d_in[12];
    const float* ad2 = (const float*)d_in[13];
    const float* b2 = (const float*)d_in[14];

    const int N = in_sizes[0] / 64;  // nodes
    const int E = in_sizes[1] / 2;   // edges (no self-loops)
    const int G = out_size / 64;     // graphs
    const int Et = E + N;            // edges incl. self-loops

    const int* srcs = edge_index;
    const int* dsts = edge_index + E;

    char* p = (char*)d_ws;
    auto alloc = [&](size_t bytes) {
        void* r = (void*)p;
        p += (bytes + 255) & ~(size_t)255;
        return r;
    };
    unsigned short* Zb = (unsigned short*)alloc((size_t)N * 256 * 2);  // bf16 z
    unsigned short* Hbhi = (unsigned short*)alloc((size_t)N * 256 * 2);
    unsigned short* Hblo = (unsigned short*)alloc((size_t)N * 256 * 2);
    unsigned short* Axhi = (unsigned short*)alloc((size_t)N * 256 * 2);
    unsigned short* Axlo = (unsigned short*)alloc((size_t)N * 256 * 2);
    float* As = (float*)alloc((size_t)N * 4 * 4);
    float* Ad = (float*)alloc((size_t)N * 4 * 4);
    int* deg = (int*)alloc((size_t)N * 4);
    int* incl = (int*)alloc((size_t)N * 4);
    int* bsum = (int*)alloc(1024 * 4);
    int* rowptr = (int*)alloc((size_t)(N + 1) * 4);
    int* cursor = (int*)alloc((size_t)N * 4);
    int* col = (int*)alloc((size_t)Et * 4);
    unsigned short* wt0h = (unsigned short*)alloc(256 * 64 * 2);
    unsigned short* wt0l = (unsigned short*)alloc(256 * 64 * 2);
    unsigned short* wt1h = (unsigned short*)alloc(256 * 256 * 2);
    unsigned short* wt1l = (unsigned short*)alloc(256 * 256 * 2);
    unsigned short* wt2h = (unsigned short*)alloc(64 * 256 * 2);
    unsigned short* wt2l = (unsigned short*)alloc(64 * 256 * 2);
    float* vs0 = (float*)alloc(4 * 64 * 4);
    float* vd0 = (float*)alloc(4 * 64 * 4);
    unsigned* enc = (unsigned*)alloc((size_t)G * 64 * 4);

    hipMemsetAsync(deg, 0, (size_t)N * 4, stream);
    hipMemsetAsync(enc, 0, (size_t)G * 64 * 4, stream);

    const int eb = (E + 255) / 256;
    const int nb = (N + 255) / 256;
    const int ab = (N + 3) / 4;
    const int gm = (N + 127) / 128;

    k_count<<<eb, 256, 0, stream>>>(dsts, E, deg);
    k_scan1<<<nb, 256, 0, stream>>>(deg, incl, bsum, N);
    k_scan2<<<1, 1024, 0, stream>>>(bsum, nb);
    k_scan3<<<nb, 256, 0, stream>>>(deg, incl, bsum, rowptr, cursor, N, nb);
    k_scatter<<<(Et + 255) / 256, 256, 0, stream>>>(srcs, dsts, E, N, cursor, col);

    k_setup<<<385, 256, 0, stream>>>(W0, W1, W2, as0, ad0, wt0h, wt0l, wt1h, wt1l,
                                     wt2h, wt2l, vs0, vd0);

    // Layer 0: As0/Ad0 from x; aggregate x; project+bias+ELU (post-GEMM)
    k_att0<<<ab, 256, 0, stream>>>(x, vs0, vd0, As, Ad, N);
    k_aggx<<<ab, 256, 0, stream>>>(x, As, Ad, rowptr, col, Axhi, Axlo, N);
    k_gemm_pe<<<dim3(gm, 4), 256, 0, stream>>>(Axhi, Axlo, wt0h, wt0l, b0, Hbhi, Hblo, N);

    // Layer 1: z GEMM (bf16 out, fused As/Ad) + all-heads aggregate
    k_gemm_z<256, 256, 128, 128, 64><<<dim3(gm, 2), 256, 0, stream>>>(
        Hbhi, Hblo, wt1h, wt1l, as1, ad1, Zb, As, Ad, N);
    k_agg4<<<ab, 256, 0, stream>>>(Zb, As, Ad, rowptr, col, b1, Hbhi, Hblo, N);

    // Layer 2: z GEMM (bf16 out, fused As/Ad) + aggregate + fused pool
    k_gemm_z<256, 64, 128, 64, 64><<<dim3(gm, 1), 256, 0, stream>>>(
        Hbhi, Hblo, wt2h, wt2l, as2, ad2, Zb, As, Ad, N);
    k_agg1<<<ab, 256, 0, stream>>>(Zb, As, Ad, rowptr, col, b2, batch, enc, N);
    k_decode<<<(G * 64 + 255) / 256, 256, 0, stream>>>(enc, (float*)d_out, G * 64);
}

// Round 12
// 369.179 us; speedup vs baseline: 1.8948x; 1.0586x over previous
//
#include <hip/hip_runtime.h>
#include <math.h>

// ---------------------------------------------------------------------------
// GAT encoder: 3 GATConv layers (H=4,4,1) + ELU + global max pool.
// Layer 0: aggregate-then-project: bf16 x-row gather (2B/lane; rounding noise
//   averages out over the softmax-weighted sum) -> aggx (bf16 hi/lo) ->
//   post-GEMM (bf16x3) with fused bias+ELU -> h0 stored bf16-single.
// Layers 1/2: project-then-aggregate. z-GEMM A-operand is bf16-single
//   (2 MFMAs: ah*bh + ah*bl; z output is bf16-rounded anyway), B keeps hi/lo.
//   z stored BF16; aggregates gather at the measured XCD-redundancy floor.
//   All aggregates hoist softmax denominators to the preamble (per-lane
//   accumulate + one wave reduce; no per-edge den adds).
// CSR build: hierarchical 3-pass parallel scan. Setup fused into one kernel.
// ---------------------------------------------------------------------------

typedef __attribute__((ext_vector_type(8))) short short8v;
typedef __attribute__((ext_vector_type(16))) float f32x16;

__device__ __forceinline__ float lrelu(float x) { return x > 0.f ? x : 0.2f * x; }

__device__ __forceinline__ unsigned short f2bf(float x) {  // RNE
    unsigned u = __float_as_uint(x);
    return (unsigned short)((u + 0x7FFFu + ((u >> 16) & 1u)) >> 16);
}
__device__ __forceinline__ float bf2f(unsigned short h) {
    return __uint_as_float(((unsigned)h) << 16);
}
__device__ __forceinline__ float readlane_f(float v, int l) {
    return __uint_as_float((unsigned)__builtin_amdgcn_readlane((int)__float_as_uint(v), l));
}

// ----------------------------- CSR build -----------------------------------
__global__ void k_count(const int* __restrict__ dst, int E, int* __restrict__ deg) {
    int e = blockIdx.x * 256 + threadIdx.x;
    if (e < E) atomicAdd(&deg[dst[e]], 1);
}

__global__ __launch_bounds__(256) void k_scan1(const int* __restrict__ deg,
                                               int* __restrict__ incl,
                                               int* __restrict__ bsum, int N) {
    const int i = blockIdx.x * 256 + threadIdx.x;
    const int lane = threadIdx.x & 63;
    const int wv = threadIdx.x >> 6;
    int sc = (i < N) ? deg[i] + 1 : 0;
#pragma unroll
    for (int off = 1; off < 64; off <<= 1) {
        int t = __shfl_up(sc, off, 64);
        if (lane >= off) sc += t;
    }
    __shared__ int wsum[4];
    if (lane == 63) wsum[wv] = sc;
    __syncthreads();
    int woff = 0;
#pragma unroll
    for (int k = 0; k < 3; k++)
        if (wv > k) woff += wsum[k];
    sc += woff;
    if (i < N) incl[i] = sc;
    if (threadIdx.x == 255) bsum[blockIdx.x] = sc;
}

__global__ __launch_bounds__(1024) void k_scan2(int* __restrict__ bsum, int nb) {
    const int t = threadIdx.x;
    const int lane = t & 63;
    const int wv = t >> 6;
    int sc = (t < nb) ? bsum[t] : 0;
#pragma unroll
    for (int off = 1; off < 64; off <<= 1) {
        int u = __shfl_up(sc, off, 64);
        if (lane >= off) sc += u;
    }
    __shared__ int wsum[16];
    if (lane == 63) wsum[wv] = sc;
    __syncthreads();
    int woff = 0;
#pragma unroll
    for (int k = 0; k < 15; k++)
        if (wv > k) woff += wsum[k];
    sc += woff;
    if (t < nb) bsum[t] = sc;
}

__global__ void k_scan3(const int* __restrict__ deg, const int* __restrict__ incl,
                        const int* __restrict__ bsum, int* __restrict__ rowptr,
                        int* __restrict__ cursor, int N, int nb) {
    int i = blockIdx.x * 256 + threadIdx.x;
    if (i < N) {
        const int off = (blockIdx.x > 0) ? bsum[blockIdx.x - 1] : 0;
        const int excl = incl[i] + off - (deg[i] + 1);
        rowptr[i] = excl;
        cursor[i] = excl;
        if (i == N - 1) rowptr[N] = bsum[nb - 1];
    }
}

__global__ void k_scatter(const int* __restrict__ src, const int* __restrict__ dst, int E,
                          int N, int* __restrict__ cursor, int* __restrict__ col) {
    int e = blockIdx.x * 256 + threadIdx.x;
    if (e < E) {
        int d = dst[e];
        int p = atomicAdd(&cursor[d], 1);
        col[p] = src[e];
    } else if (e < E + N) {
        int n = e - E;
        int p = atomicAdd(&cursor[n], 1);
        col[p] = n;
    }
}

// ----------------------------- fused setup -----------------------------------
__global__ void k_setup(const float* __restrict__ W0, const float* __restrict__ W1,
                        const float* __restrict__ W2, const float* __restrict__ as0,
                        const float* __restrict__ ad0,
                        unsigned short* __restrict__ wt0h, unsigned short* __restrict__ wt0l,
                        unsigned short* __restrict__ wt1h, unsigned short* __restrict__ wt1l,
                        unsigned short* __restrict__ wt2h, unsigned short* __restrict__ wt2l,
                        float* __restrict__ vs0, float* __restrict__ vd0) {
    const int b = blockIdx.x;
    const int t = threadIdx.x;
    if (b < 64) {
        const int i = b * 256 + t;
        const int c = i / 64, k = i % 64;
        const float xw = W0[(size_t)k * 256 + c];
        const unsigned short h = f2bf(xw);
        wt0h[i] = h;
        wt0l[i] = f2bf(xw - bf2f(h));
    } else if (b < 320) {
        const int i = (b - 64) * 256 + t;
        const int c = i / 256, k = i % 256;
        const float xw = W1[(size_t)k * 256 + c];
        const unsigned short h = f2bf(xw);
        wt1h[i] = h;
        wt1l[i] = f2bf(xw - bf2f(h));
    } else if (b < 384) {
        const int i = (b - 320) * 256 + t;
        const int c = i / 256, k = i % 256;
        const float xw = W2[(size_t)k * 64 + c];
        const unsigned short h = f2bf(xw);
        wt2h[i] = h;
        wt2l[i] = f2bf(xw - bf2f(h));
    } else {
        const int k = t;
        if (k < 64) {
            for (int h = 0; h < 4; h++) {
                float s = 0.f, d = 0.f;
                for (int c = 0; c < 64; c++) {
                    float w = W0[(size_t)k * 256 + h * 64 + c];
                    s = fmaf(w, as0[h * 64 + c], s);
                    d = fmaf(w, ad0[h * 64 + c], d);
                }
                vs0[h * 64 + k] = s;
                vd0[h * 64 + k] = d;
            }
        }
    }
}

// As0[n,h] = x[n,:] . vs0[h,:] (wave per node); also emits bf16 copy of x.
__global__ __launch_bounds__(256) void k_att0(
    const float* __restrict__ X, const float* __restrict__ vs, const float* __restrict__ vd,
    float* __restrict__ As, float* __restrict__ Ad, unsigned short* __restrict__ xb, int N) {
    const int n = blockIdx.x * 4 + (threadIdx.x >> 6);
    const int lane = threadIdx.x & 63;
    if (n >= N) return;
    const float xv = X[(size_t)n * 64 + lane];
    xb[(size_t)n * 64 + lane] = f2bf(xv);
#pragma unroll
    for (int h = 0; h < 4; h++) {
        float ps = xv * vs[h * 64 + lane];
        float pd = xv * vd[h * 64 + lane];
#pragma unroll
        for (int off = 1; off < 64; off <<= 1) {
            ps += __shfl_xor(ps, off, 64);
            pd += __shfl_xor(pd, off, 64);
        }
        if (lane == 0) {
            As[(size_t)n * 4 + h] = ps;
            Ad[(size_t)n * 4 + h] = pd;
        }
    }
}

// ----------------------------- layer-0 x-aggregate ---------------------------
// Wave per node, lane = x-dim. bf16 x gather (128B/edge serves all 4 heads).
// Weights via LDS transpose; denominators per-lane in preamble + wave reduce.
__global__ __launch_bounds__(256) void k_aggx(
    const unsigned short* __restrict__ Xb, const float* __restrict__ As,
    const float* __restrict__ Ad, const int* __restrict__ rowptr,
    const int* __restrict__ col, unsigned short* __restrict__ ohi,
    unsigned short* __restrict__ olo, int N) {
    __shared__ float wlds[4][64][4];
    const int wv = threadIdx.x >> 6;
    const int n = blockIdx.x * 4 + wv;
    const int lane = threadIdx.x & 63;
    if (n >= N) return;

    const int start = rowptr[n];
    const int total = rowptr[n + 1] - start;  // includes self-loop
    const int* __restrict__ cp = col + start;
    const float4 adn = *reinterpret_cast<const float4*>(Ad + (size_t)n * 4);

    float a0 = 0.f, a1 = 0.f, a2 = 0.f, a3 = 0.f;
    float4 dv = make_float4(0.f, 0.f, 0.f, 0.f);

    for (int base = 0; base < total; base += 64) {
        const int cnt = min(64, total - base);
        const int i = base + lane;
        int s = 0;
        float4 w = make_float4(0.f, 0.f, 0.f, 0.f);
        if (i < total) {
            s = cp[i];
            const float4 av = *reinterpret_cast<const float4*>(As + (size_t)s * 4);
            w.x = __expf(lrelu(av.x + adn.x));
            w.y = __expf(lrelu(av.y + adn.y));
            w.z = __expf(lrelu(av.z + adn.z));
            w.w = __expf(lrelu(av.w + adn.w));
        }
        dv.x += w.x; dv.y += w.y; dv.z += w.z; dv.w += w.w;
        *reinterpret_cast<float4*>(&wlds[wv][lane][0]) = w;

        int jj = 0;
        for (; jj + 4 <= cnt; jj += 4) {
            int sb[4];
            float4 wj[4];
            float xv[4];
#pragma unroll
            for (int u = 0; u < 4; u++) {
                sb[u] = __builtin_amdgcn_readlane(s, jj + u);
                wj[u] = *reinterpret_cast<const float4*>(&wlds[wv][jj + u][0]);
            }
#pragma unroll
            for (int u = 0; u < 4; u++) xv[u] = bf2f(Xb[(size_t)sb[u] * 64 + lane]);
#pragma unroll
            for (int u = 0; u < 4; u++) {
                a0 = fmaf(wj[u].x, xv[u], a0);
                a1 = fmaf(wj[u].y, xv[u], a1);
                a2 = fmaf(wj[u].z, xv[u], a2);
                a3 = fmaf(wj[u].w, xv[u], a3);
            }
        }
        for (; jj < cnt; jj++) {
            const int s0 = __builtin_amdgcn_readlane(s, jj);
            const float4 wj = *reinterpret_cast<const float4*>(&wlds[wv][jj][0]);
            const float xv = bf2f(Xb[(size_t)s0 * 64 + lane]);
            a0 = fmaf(wj.x, xv, a0);
            a1 = fmaf(wj.y, xv, a1);
            a2 = fmaf(wj.z, xv, a2);
            a3 = fmaf(wj.w, xv, a3);
        }
    }

#pragma unroll
    for (int off = 1; off < 64; off <<= 1) {
        dv.x += __shfl_xor(dv.x, off, 64);
        dv.y += __shfl_xor(dv.y, off, 64);
        dv.z += __shfl_xor(dv.z, off, 64);
        dv.w += __shfl_xor(dv.w, off, 64);
    }

    const float o[4] = {a0 / (dv.x + 1e-16f), a1 / (dv.y + 1e-16f),
                        a2 / (dv.z + 1e-16f), a3 / (dv.w + 1e-16f)};
#pragma unroll
    for (int h = 0; h < 4; h++) {
        const unsigned short hb = f2bf(o[h]);
        ohi[(size_t)n * 256 + h * 64 + lane] = hb;
        olo[(size_t)n * 256 + h * 64 + lane] = f2bf(o[h] - bf2f(hb));
    }
}

// ----------------------------- post-GEMM (layer 0) ---------------------------
// h0[n, h*64+c] = ELU(aggx[n, h*64+:64] @ W0[:, h*64+c] + b0). Output bf16.
__global__ __launch_bounds__(256) void k_gemm_pe(
    const unsigned short* __restrict__ Ahi, const unsigned short* __restrict__ Alo,
    const unsigned short* __restrict__ Bhi, const unsigned short* __restrict__ Blo,
    const float* __restrict__ bias, unsigned short* __restrict__ Ohi, int N) {
    constexpr int LD = 40, BM = 128, K = 64;
    __shared__ unsigned short sa[2][BM * LD];
    __shared__ unsigned short sb[2][64 * LD];

    const int tid = threadIdx.x;
    const int n0 = blockIdx.x * BM;
    const int hh = blockIdx.y;
    const int wid = tid >> 6, lane = tid & 63;

    const unsigned short* __restrict__ Ah = Ahi + hh * 64;
    const unsigned short* __restrict__ Al = Alo + hh * 64;
    const unsigned short* __restrict__ Bh = Bhi + hh * 64 * K;
    const unsigned short* __restrict__ Bl = Blo + hh * 64 * K;

    f32x16 acc[2];
#pragma unroll
    for (int n = 0; n < 2; n++)
#pragma unroll
        for (int i = 0; i < 16; i++) acc[n][i] = 0.f;

    const int srow = tid >> 2, schk = tid & 3;

    for (int kb = 0; kb < K; kb += 32) {
        __syncthreads();
#pragma unroll
        for (int rr = 0; rr < 2; rr++) {
            const int r = srow + rr * 64;
            const int row = n0 + r;
            short8v vh = {0, 0, 0, 0, 0, 0, 0, 0}, vl = {0, 0, 0, 0, 0, 0, 0, 0};
            if (row < N) {
                vh = *reinterpret_cast<const short8v*>(Ah + (size_t)row * 256 + kb + schk * 8);
                vl = *reinterpret_cast<const short8v*>(Al + (size_t)row * 256 + kb + schk * 8);
            }
            *reinterpret_cast<short8v*>(&sa[0][r * LD + schk * 8]) = vh;
            *reinterpret_cast<short8v*>(&sa[1][r * LD + schk * 8]) = vl;
        }
        {
            const short8v vh =
                *reinterpret_cast<const short8v*>(Bh + (size_t)srow * K + kb + schk * 8);
            const short8v vl =
                *reinterpret_cast<const short8v*>(Bl + (size_t)srow * K + kb + schk * 8);
            *reinterpret_cast<short8v*>(&sb[0][srow * LD + schk * 8]) = vh;
            *reinterpret_cast<short8v*>(&sb[1][srow * LD + schk * 8]) = vl;
        }
        __syncthreads();
#pragma unroll
        for (int ks = 0; ks < 2; ks++) {
            const int koff = ks * 16 + (lane >> 5) * 8;
            const int ar = wid * 32 + (lane & 31);
            const short8v ah = *reinterpret_cast<const short8v*>(&sa[0][ar * LD + koff]);
            const short8v al = *reinterpret_cast<const short8v*>(&sa[1][ar * LD + koff]);
            short8v bh[2], bl[2];
#pragma unroll
            for (int n = 0; n < 2; n++) {
                const int br = n * 32 + (lane & 31);
                bh[n] = *reinterpret_cast<const short8v*>(&sb[0][br * LD + koff]);
                bl[n] = *reinterpret_cast<const short8v*>(&sb[1][br * LD + koff]);
            }
#pragma unroll
            for (int n = 0; n < 2; n++) {
                acc[n] = __builtin_amdgcn_mfma_f32_32x32x16_bf16(ah, bh[n], acc[n], 0, 0, 0);
                acc[n] = __builtin_amdgcn_mfma_f32_32x32x16_bf16(ah, bl[n], acc[n], 0, 0, 0);
                acc[n] = __builtin_amdgcn_mfma_f32_32x32x16_bf16(al, bh[n], acc[n], 0, 0, 0);
            }
        }
    }

    const int rowb = n0 + wid * 32 + 4 * (lane >> 5);
#pragma unroll
    for (int n = 0; n < 2; n++) {
        const int c = (lane & 31) + n * 32;
        const float bv = bias[hh * 64 + c];
#pragma unroll
        for (int r = 0; r < 16; r++) {
            const int row = rowb + (r & 3) + 8 * (r >> 2);
            if (row < N) {
                float ov = acc[n][r] + bv;
                ov = (ov > 0.f) ? ov : expm1f(ov);
                Ohi[(size_t)row * 256 + hh * 64 + c] = f2bf(ov);
            }
        }
    }
}

// ----------------------------- z GEMM (layers 1,2) ---------------------------
// Zb[N,COLS] (BF16) = A(bf16 single) @ W(hi/lo): 2 MFMAs (ah*bh + ah*bl).
// Epilogue emits As/Ad = z . att (WN=64; 32-lane shfl butterfly).
template <int K, int COLS, int BM, int BN, int WN>
__global__ __launch_bounds__(256) void k_gemm_z(
    const unsigned short* __restrict__ Ahi,
    const unsigned short* __restrict__ Bhi, const unsigned short* __restrict__ Blo,
    const float* __restrict__ att_src, const float* __restrict__ att_dst,
    unsigned short* __restrict__ Zb, float* __restrict__ As, float* __restrict__ Ad, int N) {
    constexpr int LD = 40;
    constexpr int WAVES_N = BN / WN;
    constexpr int WAVES_M = 4 / WAVES_N;
    constexpr int WM = BM / WAVES_M;
    constexpr int MW = WM / 32, NW = WN / 32;
    constexpr int H = COLS / 64;
    __shared__ unsigned short sa[BM * LD];
    __shared__ unsigned short sb[2][BN * LD];

    const int tid = threadIdx.x;
    const int n0 = blockIdx.x * BM;
    const int c0 = blockIdx.y * BN;
    const int wid = tid >> 6, lane = tid & 63;
    const int wr = wid / WAVES_N, wc = wid % WAVES_N;

    f32x16 acc[MW][NW];
#pragma unroll
    for (int m = 0; m < MW; m++)
#pragma unroll
        for (int n = 0; n < NW; n++)
#pragma unroll
            for (int i = 0; i < 16; i++) acc[m][n][i] = 0.f;

    const int srow = tid >> 2, schk = tid & 3;

    for (int kb = 0; kb < K; kb += 32) {
        __syncthreads();
#pragma unroll
        for (int rr = 0; rr < BM / 64; rr++) {
            const int r = srow + rr * 64;
            const int row = n0 + r;
            short8v vh = {0, 0, 0, 0, 0, 0, 0, 0};
            if (row < N)
                vh = *reinterpret_cast<const short8v*>(Ahi + (size_t)row * K + kb + schk * 8);
            *reinterpret_cast<short8v*>(&sa[r * LD + schk * 8]) = vh;
        }
#pragma unroll
        for (int rr = 0; rr < BN / 64; rr++) {
            const int cc = srow + rr * 64;
            const short8v vh =
                *reinterpret_cast<const short8v*>(Bhi + (size_t)(c0 + cc) * K + kb + schk * 8);
            const short8v vl =
                *reinterpret_cast<const short8v*>(Blo + (size_t)(c0 + cc) * K + kb + schk * 8);
            *reinterpret_cast<short8v*>(&sb[0][cc * LD + schk * 8]) = vh;
            *reinterpret_cast<short8v*>(&sb[1][cc * LD + schk * 8]) = vl;
        }
        __syncthreads();
#pragma unroll
        for (int ks = 0; ks < 2; ks++) {
            const int koff = ks * 16 + (lane >> 5) * 8;
            short8v ah[MW], bh[NW], bl[NW];
#pragma unroll
            for (int m = 0; m < MW; m++) {
                const int ar = wr * WM + m * 32 + (lane & 31);
                ah[m] = *reinterpret_cast<const short8v*>(&sa[ar * LD + koff]);
            }
#pragma unroll
            for (int n = 0; n < NW; n++) {
                const int br = wc * WN + n * 32 + (lane & 31);
                bh[n] = *reinterpret_cast<const short8v*>(&sb[0][br * LD + koff]);
                bl[n] = *reinterpret_cast<const short8v*>(&sb[1][br * LD + koff]);
            }
#pragma unroll
            for (int m = 0; m < MW; m++)
#pragma unroll
                for (int n = 0; n < NW; n++) {
                    acc[m][n] = __builtin_amdgcn_mfma_f32_32x32x16_bf16(ah[m], bh[n], acc[m][n], 0, 0, 0);
                    acc[m][n] = __builtin_amdgcn_mfma_f32_32x32x16_bf16(ah[m], bl[n], acc[m][n], 0, 0, 0);
                }
        }
    }

    const int colb = c0 + wc * WN + (lane & 31);
    const int rowb = n0 + wr * WM + 4 * (lane >> 5);
#pragma unroll
    for (int m = 0; m < MW; m++)
#pragma unroll
        for (int n = 0; n < NW; n++)
#pragma unroll
            for (int r = 0; r < 16; r++) {
                const int row = rowb + m * 32 + (r & 3) + 8 * (r >> 2);
                if (row < N) Zb[(size_t)row * COLS + colb + n * 32] = f2bf(acc[m][n][r]);
            }

    const int hh = (c0 + wc * WN) >> 6;
    float asv[NW], adv[NW];
#pragma unroll
    for (int n = 0; n < NW; n++) {
        asv[n] = att_src[colb + n * 32];
        adv[n] = att_dst[colb + n * 32];
    }
#pragma unroll
    for (int m = 0; m < MW; m++)
#pragma unroll
        for (int r = 0; r < 16; r++) {
            const int row = rowb + m * 32 + (r & 3) + 8 * (r >> 2);
            float ps = 0.f, pd = 0.f;
#pragma unroll
            for (int n = 0; n < NW; n++) {
                ps = fmaf(acc[m][n][r], asv[n], ps);
                pd = fmaf(acc[m][n][r], adv[n], pd);
            }
#pragma unroll
            for (int off = 1; off < 32; off <<= 1) {
                ps += __shfl_xor(ps, off, 64);
                pd += __shfl_xor(pd, off, 64);
            }
            if ((lane & 31) == 0 && row < N) {
                As[(size_t)row * H + hh] = ps;
                Ad[(size_t)row * H + hh] = pd;
            }
        }
}

// ----------------------------- global max pool helpers -----------------------
__device__ __forceinline__ unsigned fenc(float f) {
    unsigned u = __float_as_uint(f);
    return (u & 0x80000000u) ? ~u : (u | 0x80000000u);
}

// ----------------------------- layer-1 aggregate (all heads) -----------------
// One wave per node; head h = lane>>4, channels (lane&15)*4..+3. One ushort4
// load/edge/lane (512B/edge wave-wide). Weights via LDS transpose; den per-lane
// preamble + wave reduce. Output: h1 as bf16-single plane.
__global__ __launch_bounds__(256) void k_agg4(
    const unsigned short* __restrict__ Zb, const float* __restrict__ As,
    const float* __restrict__ Ad, const int* __restrict__ rowptr,
    const int* __restrict__ col, const float* __restrict__ bias,
    unsigned short* __restrict__ ohi, int N) {
    __shared__ float wlds[4][64][4];
    const int wv = threadIdx.x >> 6;
    const int n = blockIdx.x * 4 + wv;
    const int lane = threadIdx.x & 63;
    if (n >= N) return;
    const int h = lane >> 4;

    const int start = rowptr[n];
    const int total = rowptr[n + 1] - start;  // includes self-loop
    const int* __restrict__ cp = col + start;
    const float4 adn = *reinterpret_cast<const float4*>(Ad + (size_t)n * 4);
    const unsigned short* __restrict__ Zl = Zb + lane * 4;

    float a0 = 0.f, a1 = 0.f, a2 = 0.f, a3 = 0.f;
    float4 dv = make_float4(0.f, 0.f, 0.f, 0.f);

    for (int base = 0; base < total; base += 64) {
        const int cnt = min(64, total - base);
        const int i = base + lane;
        int s = 0;
        float4 w = make_float4(0.f, 0.f, 0.f, 0.f);
        if (i < total) {
            s = cp[i];
            const float4 av = *reinterpret_cast<const float4*>(As + (size_t)s * 4);
            w.x = __expf(lrelu(av.x + adn.x));
            w.y = __expf(lrelu(av.y + adn.y));
            w.z = __expf(lrelu(av.z + adn.z));
            w.w = __expf(lrelu(av.w + adn.w));
        }
        dv.x += w.x; dv.y += w.y; dv.z += w.z; dv.w += w.w;
        *reinterpret_cast<float4*>(&wlds[wv][lane][0]) = w;

        int jj = 0;
        for (; jj + 8 <= cnt; jj += 8) {
            int sb[8];
            float ws[8];
            ushort4 zb[8];
#pragma unroll
            for (int u = 0; u < 8; u++) {
                sb[u] = __builtin_amdgcn_readlane(s, jj + u);
                ws[u] = wlds[wv][jj + u][h];
            }
#pragma unroll
            for (int u = 0; u < 8; u++)
                zb[u] = *reinterpret_cast<const ushort4*>(Zl + (size_t)sb[u] * 256);
#pragma unroll
            for (int u = 0; u < 8; u++) {
                a0 = fmaf(ws[u], bf2f(zb[u].x), a0);
                a1 = fmaf(ws[u], bf2f(zb[u].y), a1);
                a2 = fmaf(ws[u], bf2f(zb[u].z), a2);
                a3 = fmaf(ws[u], bf2f(zb[u].w), a3);
            }
        }
        for (; jj + 4 <= cnt; jj += 4) {
            int sb[4];
            float ws[4];
            ushort4 zb[4];
#pragma unroll
            for (int u = 0; u < 4; u++) {
                sb[u] = __builtin_amdgcn_readlane(s, jj + u);
                ws[u] = wlds[wv][jj + u][h];
            }
#pragma unroll
            for (int u = 0; u < 4; u++)
                zb[u] = *reinterpret_cast<const ushort4*>(Zl + (size_t)sb[u] * 256);
#pragma unroll
            for (int u = 0; u < 4; u++) {
                a0 = fmaf(ws[u], bf2f(zb[u].x), a0);
                a1 = fmaf(ws[u], bf2f(zb[u].y), a1);
                a2 = fmaf(ws[u], bf2f(zb[u].z), a2);
                a3 = fmaf(ws[u], bf2f(zb[u].w), a3);
            }
        }
        for (; jj < cnt; jj++) {
            const int s0 = __builtin_amdgcn_readlane(s, jj);
            const float ws = wlds[wv][jj][h];
            const ushort4 zb = *reinterpret_cast<const ushort4*>(Zl + (size_t)s0 * 256);
            a0 = fmaf(ws, bf2f(zb.x), a0);
            a1 = fmaf(ws, bf2f(zb.y), a1);
            a2 = fmaf(ws, bf2f(zb.z), a2);
            a3 = fmaf(ws, bf2f(zb.w), a3);
        }
    }

#pragma unroll
    for (int off = 1; off < 64; off <<= 1) {
        dv.x += __shfl_xor(dv.x, off, 64);
        dv.y += __shfl_xor(dv.y, off, 64);
        dv.z += __shfl_xor(dv.z, off, 64);
        dv.w += __shfl_xor(dv.w, off, 64);
    }
    const float den = (h == 0) ? dv.x : (h == 1) ? dv.y : (h == 2) ? dv.z : dv.w;
    const float inv = 1.f / (den + 1e-16f);
    float o[4] = {a0, a1, a2, a3};
#pragma unroll
    for (int j = 0; j < 4; j++) {
        float ov = o[j] * inv + bias[lane * 4 + j];
        o[j] = (ov > 0.f) ? ov : expm1f(ov);
    }
    const ushort4 vh = make_ushort4(f2bf(o[0]), f2bf(o[1]), f2bf(o[2]), f2bf(o[3]));
    *reinterpret_cast<ushort4*>(ohi + (size_t)n * 256 + lane * 4) = vh;
}

// ----------------------------- layer-2 aggregate + pool ----------------------
__global__ __launch_bounds__(256) void k_agg1(
    const unsigned short* __restrict__ Zb, const float* __restrict__ As,
    const float* __restrict__ Ad, const int* __restrict__ rowptr,
    const int* __restrict__ col, const float* __restrict__ bias,
    const int* __restrict__ batch, unsigned* __restrict__ enc, int N) {
    const int n = blockIdx.x * 4 + (threadIdx.x >> 6);
    const int lane = threadIdx.x & 63;
    if (n >= N) return;

    const int start = rowptr[n];
    const int total = rowptr[n + 1] - start;  // includes self-loop
    const int* __restrict__ cp = col + start;
    const float adn = Ad[n];

    float acc = 0.f, denom = 0.f;

    for (int base = 0; base < total; base += 64) {
        const int cnt = min(64, total - base);
        const int i = base + lane;
        int s = 0;
        float w = 0.f;
        if (i < total) {
            s = cp[i];
            w = __expf(lrelu(As[s] + adn));
        }
        denom += w;

        int jj = 0;
        for (; jj + 8 <= cnt; jj += 8) {
            int sb[8];
            float wb[8], zb[8];
#pragma unroll
            for (int u = 0; u < 8; u++) {
                sb[u] = __builtin_amdgcn_readlane(s, jj + u);
                wb[u] = readlane_f(w, jj + u);
            }
#pragma unroll
            for (int u = 0; u < 8; u++) zb[u] = bf2f(Zb[(size_t)sb[u] * 64 + lane]);
#pragma unroll
            for (int u = 0; u < 8; u++) acc = fmaf(wb[u], zb[u], acc);
        }
        for (; jj < cnt; jj++) {
            const int s0 = __builtin_amdgcn_readlane(s, jj);
            const float w0 = readlane_f(w, jj);
            acc = fmaf(w0, bf2f(Zb[(size_t)s0 * 64 + lane]), acc);
        }
    }

#pragma unroll
    for (int off = 1; off < 64; off <<= 1) denom += __shfl_xor(denom, off, 64);

    const float ov = acc / (denom + 1e-16f) + bias[lane];
    const int g = batch[n];
    atomicMax(&enc[g * 64 + lane], fenc(ov));
}

__global__ void k_decode(const unsigned* __restrict__ enc, float* __restrict__ out, int M) {
    int id = blockIdx.x * 256 + threadIdx.x;
    if (id < M) {
        unsigned e = enc[id];
        unsigned u = (e & 0x80000000u) ? (e & 0x7FFFFFFFu) : ~e;
        out[id] = __uint_as_float(u);
    }
}

// ----------------------------- launch ---------------------------------------
extern "C" void kernel_launch(void* const* d_in, const int* in_sizes, int n_in,
                              void* d_out, int out_size, void* d_ws, size_t ws_size,
                              hipStream_t stream) {
    const float* x = (const float*)d_in[0];
    const int* edge_index = (const int*)d_in[1];
    const int* batch = (const int*)d_in[2];
    const float* W0 = (const float*)d_in[3];
    const float* as0 = (const float*)d_in[4];
    const float* ad0 = (const float*)d_in[5];
    const float* b0 = (const float*)d_in[6];
    const float* W1 = (const float*)d_in[7];
    const float* as1 = (const float*)d_in[8];
    const float* ad1 = (const float*)d_in[9];
    const float* b1 = (const float*)d_in[10];
    const float* W2 = (const float*)d_in[11];
    const float* as2 = (const float*)d_in[12];
    const float* ad2 = (const float*)d_in[13];
    const float* b2 = (const float*)d_in[14];

    const int N = in_sizes[0] / 64;  // nodes
    const int E = in_sizes[1] / 2;   // edges (no self-loops)
    const int G = out_size / 64;     // graphs
    const int Et = E + N;            // edges incl. self-loops

    const int* srcs = edge_index;
    const int* dsts = edge_index + E;

    char* p = (char*)d_ws;
    auto alloc = [&](size_t bytes) {
        void* r = (void*)p;
        p += (bytes + 255) & ~(size_t)255;
        return r;
    };
    unsigned short* Zb = (unsigned short*)alloc((size_t)N * 256 * 2);   // bf16 z
    unsigned short* Hb = (unsigned short*)alloc((size_t)N * 256 * 2);   // h0/h1 bf16
    unsigned short* xb = (unsigned short*)alloc((size_t)N * 64 * 2);    // bf16 x
    unsigned short* Axhi = (unsigned short*)alloc((size_t)N * 256 * 2); // aggx hi
    unsigned short* Axlo = (unsigned short*)alloc((size_t)N * 256 * 2); // aggx lo
    float* As = (float*)alloc((size_t)N * 4 * 4);
    float* Ad = (float*)alloc((size_t)N * 4 * 4);
    int* deg = (int*)alloc((size_t)N * 4);
    int* incl = (int*)alloc((size_t)N * 4);
    int* bsum = (int*)alloc(1024 * 4);
    int* rowptr = (int*)alloc((size_t)(N + 1) * 4);
    int* cursor = (int*)alloc((size_t)N * 4);
    int* col = (int*)alloc((size_t)Et * 4);
    unsigned short* wt0h = (unsigned short*)alloc(256 * 64 * 2);
    unsigned short* wt0l = (unsigned short*)alloc(256 * 64 * 2);
    unsigned short* wt1h = (unsigned short*)alloc(256 * 256 * 2);
    unsigned short* wt1l = (unsigned short*)alloc(256 * 256 * 2);
    unsigned short* wt2h = (unsigned short*)alloc(64 * 256 * 2);
    unsigned short* wt2l = (unsigned short*)alloc(64 * 256 * 2);
    float* vs0 = (float*)alloc(4 * 64 * 4);
    float* vd0 = (float*)alloc(4 * 64 * 4);
    unsigned* enc = (unsigned*)alloc((size_t)G * 64 * 4);

    hipMemsetAsync(deg, 0, (size_t)N * 4, stream);
    hipMemsetAsync(enc, 0, (size_t)G * 64 * 4, stream);

    const int eb = (E + 255) / 256;
    const int nb = (N + 255) / 256;
    const int ab = (N + 3) / 4;
    const int gm = (N + 127) / 128;

    k_count<<<eb, 256, 0, stream>>>(dsts, E, deg);
    k_scan1<<<nb, 256, 0, stream>>>(deg, incl, bsum, N);
    k_scan2<<<1, 1024, 0, stream>>>(bsum, nb);
    k_scan3<<<nb, 256, 0, stream>>>(deg, incl, bsum, rowptr, cursor, N, nb);
    k_scatter<<<(Et + 255) / 256, 256, 0, stream>>>(srcs, dsts, E, N, cursor, col);

    k_setup<<<385, 256, 0, stream>>>(W0, W1, W2, as0, ad0, wt0h, wt0l, wt1h, wt1l,
                                     wt2h, wt2l, vs0, vd0);

    // Layer 0: As0/Ad0 + bf16 x copy; aggregate x (bf16 gather); post-GEMM
    k_att0<<<ab, 256, 0, stream>>>(x, vs0, vd0, As, Ad, xb, N);
    k_aggx<<<ab, 256, 0, stream>>>(xb, As, Ad, rowptr, col, Axhi, Axlo, N);
    k_gemm_pe<<<dim3(gm, 4), 256, 0, stream>>>(Axhi, Axlo, wt0h, wt0l, b0, Hb, N);

    // Layer 1: z GEMM (A=bf16 single, 2-MFMA) + all-heads aggregate
    k_gemm_z<256, 256, 128, 128, 64><<<dim3(gm, 2), 256, 0, stream>>>(
        Hb, wt1h, wt1l, as1, ad1, Zb, As, Ad, N);
    k_agg4<<<ab, 256, 0, stream>>>(Zb, As, Ad, rowptr, col, b1, Hb, N);

    // Layer 2: z GEMM + aggregate + fused pool
    k_gemm_z<256, 64, 128, 64, 64><<<dim3(gm, 1), 256, 0, stream>>>(
        Hb, wt2h, wt2l, as2, ad2, Zb, As, Ad, N);
    k_agg1<<<ab, 256, 0, stream>>>(Zb, As, Ad, rowptr, col, b2, batch, enc, N);
    k_decode<<<(G * 64 + 255) / 256, 256, 0, stream>>>(enc, (float*)d_out, G * 64);
}